// Round 4
// baseline (247.287 us; speedup 1.0000x reference)
//
#include <hip/hip_runtime.h>

#define NSEQ 4096
#define CHN 256

typedef __attribute__((ext_vector_type(8))) short short8;
typedef __attribute__((ext_vector_type(4))) float f32x4;
typedef __attribute__((ext_vector_type(4))) unsigned short us4;
typedef unsigned short u16;

// fp32 -> bf16 round-to-nearest-even
__device__ __forceinline__ u16 f2b(float f) {
  unsigned u = __builtin_bit_cast(unsigned, f);
  unsigned r = (u + 0x7fffu + ((u >> 16) & 1u)) >> 16;
  return (u16)r;
}
__device__ __forceinline__ float b2f(u16 h) {
  unsigned u = ((unsigned)h) << 16;
  return __builtin_bit_cast(float, u);
}

// ws layout in u16 elements
#define QH_OFF   0u          // [B][N][32]  theta^T hi (pre-scaled by log2e)
#define QL_OFF   524288u     // [B][N][32]  theta^T lo
#define KH_OFF   1048576u    // [B][N][32]  phi^T hi
#define KL_OFF   1572864u    // [B][N][32]  phi^T lo
#define V_OFF    2097152u    // [B][128][N] g
#define WQKH_OFF 4194304u    // [64][256]   (Wt*log2e | Wp) hi
#define WQKL_OFF 4210688u    // [64][256]   (Wt*log2e | Wp) lo
#define WG_OFF   4227072u    // [128][256]  Wg
#define WO_OFF   4259840u    // [256][128]  Wo

// ---------------- kernel 0: weight prep (fp32 -> bf16 / hi+lo) ----------------
__global__ __launch_bounds__(256) void prep_weights(
    const float* __restrict__ Wt, const float* __restrict__ Wp,
    const float* __restrict__ Wg, const float* __restrict__ Wo,
    u16* __restrict__ Wqkh, u16* __restrict__ Wqkl,
    u16* __restrict__ Wgb, u16* __restrict__ Wob) {
  int gid = blockIdx.x * 256 + threadIdx.x;  // 80 blocks -> 20480 threads
  if (gid < 4096) {                          // 64*256/4 float4 tasks, hi/lo split
    int row = gid >> 6;
    int c = (gid & 63) * 4;
    const float* src;
    float scale = 1.0f;
    if (row < 32) { src = Wt + row * 256; scale = 1.44269504088896340736f; }
    else          { src = Wp + (row - 32) * 256; }
    float4 v = *(const float4*)(src + c);
    float w0 = v.x * scale, w1 = v.y * scale, w2 = v.z * scale, w3 = v.w * scale;
    us4 hi = { f2b(w0), f2b(w1), f2b(w2), f2b(w3) };
    us4 lo = { f2b(w0 - b2f(hi[0])), f2b(w1 - b2f(hi[1])),
               f2b(w2 - b2f(hi[2])), f2b(w3 - b2f(hi[3])) };
    *(us4*)(Wqkh + row * 256 + c) = hi;
    *(us4*)(Wqkl + row * 256 + c) = lo;
  } else if (gid < 12288) {                  // Wg: 128*256/4 float4 tasks
    int g = (gid - 4096) * 4;
    float4 v = *(const float4*)(Wg + g);
    us4 o = { f2b(v.x), f2b(v.y), f2b(v.z), f2b(v.w) };
    *(us4*)(Wgb + g) = o;
  } else {                                   // Wo: 256*128/4 float4 tasks
    int g = (gid - 12288) * 4;
    float4 v = *(const float4*)(Wo + g);
    us4 o = { f2b(v.x), f2b(v.y), f2b(v.z), f2b(v.w) };
    *(us4*)(Wob + g) = o;
  }
}

// ---------------- kernel 1: QKV projection, 4-way output-slice split ----------------
// (unchanged from round 3 — awaiting counters before touching it)
__global__ __launch_bounds__(256, 4) void proj_qkv(
    const float* __restrict__ x,
    const u16* __restrict__ Wqkh, const u16* __restrict__ Wqkl,
    const u16* __restrict__ Wgb,
    u16* __restrict__ QbH, u16* __restrict__ QbL,
    u16* __restrict__ KbH, u16* __restrict__ KbL,
    u16* __restrict__ Vb) {
  int tid = threadIdx.x;
  int wave = tid >> 6, lane = tid & 63;
  int l15 = lane & 15, quad = lane >> 4;
  int slice = blockIdx.x >> 8;
  int tb = blockIdx.x & 255;
  int b = tb >> 6;
  int n0 = (tb & 63) * 64;
  int pos = n0 + wave * 16 + l15;
  const float* xb = x + (size_t)b * CHN * NSEQ + pos;
  int nbase = n0 + wave * 16 + quad * 4;

  if (slice < 2) {
    const u16* Wh = Wqkh + slice * 32 * 256;
    const u16* Wl = Wqkl + slice * 32 * 256;
    f32x4 acc[2];
    acc[0] = (f32x4){0.f, 0.f, 0.f, 0.f};
    acc[1] = (f32x4){0.f, 0.f, 0.f, 0.f};
#pragma unroll
    for (int kc = 0; kc < 8; kc++) {
      short8 ahi, alo;
#pragma unroll
      for (int j = 0; j < 8; j++) {
        float xv = xb[(size_t)(kc * 32 + quad * 8 + j) * NSEQ];
        u16 hi = f2b(xv);
        ahi[j] = (short)hi;
        alo[j] = (short)f2b(xv - b2f(hi));
      }
#pragma unroll
      for (int ot = 0; ot < 2; ot++) {
        size_t off = (size_t)(ot * 16 + l15) * 256 + kc * 32 + quad * 8;
        short8 bh = *(const short8*)(Wh + off);
        short8 bl = *(const short8*)(Wl + off);
        acc[ot] = __builtin_amdgcn_mfma_f32_16x16x32_bf16(alo, bh, acc[ot], 0, 0, 0);
        acc[ot] = __builtin_amdgcn_mfma_f32_16x16x32_bf16(ahi, bl, acc[ot], 0, 0, 0);
        acc[ot] = __builtin_amdgcn_mfma_f32_16x16x32_bf16(ahi, bh, acc[ot], 0, 0, 0);
      }
    }
    u16* Hp = (slice == 0) ? QbH : KbH;
    u16* Lp = (slice == 0) ? QbL : KbL;
#pragma unroll
    for (int ot = 0; ot < 2; ot++) {
#pragma unroll
      for (int r = 0; r < 4; r++) {
        float v = acc[ot][r];
        u16 hi = f2b(v);
        u16 lo = f2b(v - b2f(hi));
        size_t nrow = (size_t)(b * NSEQ + nbase + r) * 32 + ot * 16 + l15;
        Hp[nrow] = hi; Lp[nrow] = lo;
      }
    }
  } else {
    const u16* Wg2 = Wgb + (size_t)(slice - 2) * 64 * 256;
    f32x4 acc[4];
#pragma unroll
    for (int oi = 0; oi < 4; oi++) acc[oi] = (f32x4){0.f, 0.f, 0.f, 0.f};
#pragma unroll
    for (int kc = 0; kc < 8; kc++) {
      short8 ahi;
#pragma unroll
      for (int j = 0; j < 8; j++)
        ahi[j] = (short)f2b(xb[(size_t)(kc * 32 + quad * 8 + j) * NSEQ]);
#pragma unroll
      for (int oi = 0; oi < 4; oi++) {
        short8 bg = *(const short8*)(Wg2 + (size_t)(oi * 16 + l15) * 256 + kc * 32 + quad * 8);
        acc[oi] = __builtin_amdgcn_mfma_f32_16x16x32_bf16(ahi, bg, acc[oi], 0, 0, 0);
      }
    }
#pragma unroll
    for (int oi = 0; oi < 4; oi++) {
      int c = (slice - 2) * 64 + oi * 16 + l15;
      us4 pk = { f2b(acc[oi][0]), f2b(acc[oi][1]), f2b(acc[oi][2]), f2b(acc[oi][3]) };
      *(us4*)(Vb + (size_t)(b * 128 + c) * NSEQ + nbase) = pk;
    }
  }
}

// ---------------- kernel 2: fused flash attention + Wo + epilogue (v3) ----------------
// No LDS in the main loop: key-row permutation makes the exp'd QK^T C-layout output
// directly the B-operand of PV (V as A-operand, same row permutation), and the PV
// C-layout output directly the B-operand of the Wo GEMM.
// 256-thread blocks: 4 waves = 4 key-splits of 1024 keys, 16 Q-rows per block.
// grid = 4 batches x 256 row-tiles = 1024 blocks = 4 blocks/CU = 16 waves/CU.
__global__ __launch_bounds__(256, 4) void flash_attn(
    const u16* __restrict__ QbH, const u16* __restrict__ QbL,
    const u16* __restrict__ KbH, const u16* __restrict__ KbL,
    const u16* __restrict__ Vb, const u16* __restrict__ Wob,
    const float* __restrict__ x, const float* __restrict__ gammap,
    float* __restrict__ out) {
  __shared__ alignas(16) f32x4 Comb[8][64];   // 8 KB split-K combine
  __shared__ float CombL[64];
  __shared__ alignas(16) short8 BC[64][4];    // 4 KB attn B-frag broadcast

  int tid = threadIdx.x;
  int wave = tid >> 6, lane = tid & 63;
  int l15 = lane & 15, quad = lane >> 4;
  int b = blockIdx.x & 3;                     // batch in low bits -> XCD affinity
  int tile = blockIdx.x >> 2;
  int n0 = tile * 16;
  int ms = wave * 1024;                       // this wave's key split
  int rk = ((l15 >> 2) << 3) + (l15 & 3);     // permuted row-in-tile

  size_t qoff = (size_t)(b * NSEQ + n0 + l15) * 32 + quad * 8;
  short8 qh = *(const short8*)(QbH + qoff);
  short8 ql = *(const short8*)(QbL + qoff);

  const u16* KpH = KbH + (size_t)b * NSEQ * 32 + (size_t)(ms + rk) * 32 + quad * 8;
  const u16* KpL = KbL + (size_t)b * NSEQ * 32 + (size_t)(ms + rk) * 32 + quad * 8;
  const u16* Vp  = Vb + (size_t)b * 128 * NSEQ + (size_t)rk * NSEQ + ms + quad * 8;

  f32x4 acc[8];
#pragma unroll
  for (int vt = 0; vt < 8; vt++) acc[vt] = (f32x4){0.f, 0.f, 0.f, 0.f};
  float lsum = 0.f;

  // prefetch chunk 0
  short8 kh0 = *(const short8*)(KpH);
  short8 kh1 = *(const short8*)(KpH + 128);   // +4 permuted rows
  short8 kl0 = *(const short8*)(KpL);
  short8 kl1 = *(const short8*)(KpL + 128);
  short8 vf[8];
#pragma unroll
  for (int vt = 0; vt < 8; vt++)
    vf[vt] = *(const short8*)(Vp + (size_t)((vt >> 1) * 32 + (vt & 1) * 4) * NSEQ);

  for (int ci = 0; ci < 32; ci++) {
    int cn = (ci + 1) & 31;                   // next chunk (wraps harmlessly)
    short8 nkh0 = *(const short8*)(KpH + (size_t)cn * 1024);
    short8 nkh1 = *(const short8*)(KpH + (size_t)cn * 1024 + 128);
    short8 nkl0 = *(const short8*)(KpL + (size_t)cn * 1024);
    short8 nkl1 = *(const short8*)(KpL + (size_t)cn * 1024 + 128);
    short8 nvf[8];
#pragma unroll
    for (int vt = 0; vt < 8; vt++)
      nvf[vt] = *(const short8*)(Vp + (size_t)((vt >> 1) * 32 + (vt & 1) * 4) * NSEQ + cn * 32);

    // S^T tiles over permuted keys; hi/lo split, small terms first.
    // C-layout row m -> global key: tile0 = quad*8+r, tile1 = quad*8+4+r
    f32x4 z = (f32x4){0.f, 0.f, 0.f, 0.f};
    f32x4 s0 = __builtin_amdgcn_mfma_f32_16x16x32_bf16(kl0, qh, z, 0, 0, 0);
    s0 = __builtin_amdgcn_mfma_f32_16x16x32_bf16(kh0, ql, s0, 0, 0, 0);
    s0 = __builtin_amdgcn_mfma_f32_16x16x32_bf16(kh0, qh, s0, 0, 0, 0);
    f32x4 s1 = __builtin_amdgcn_mfma_f32_16x16x32_bf16(kl1, qh, z, 0, 0, 0);
    s1 = __builtin_amdgcn_mfma_f32_16x16x32_bf16(kh1, ql, s1, 0, 0, 0);
    s1 = __builtin_amdgcn_mfma_f32_16x16x32_bf16(kh1, qh, s1, 0, 0, 0);

    // exp2 -> packed short8 == B-frag of PV (k = quad*8 + j)
    short8 pp;
#pragma unroll
    for (int r = 0; r < 4; r++) {
      float e0 = exp2f(s0[r]);
      float e1 = exp2f(s1[r]);
      lsum += e0 + e1;
      pp[r] = (short)f2b(e0);
      pp[r + 4] = (short)f2b(e1);
    }
#pragma unroll
    for (int vt = 0; vt < 8; vt++)
      acc[vt] = __builtin_amdgcn_mfma_f32_16x16x32_bf16(vf[vt], pp, acc[vt], 0, 0, 0);

    kh0 = nkh0; kh1 = nkh1; kl0 = nkl0; kl1 = nkl1;
#pragma unroll
    for (int vt = 0; vt < 8; vt++) vf[vt] = nvf[vt];
  }

  // ---- split-K combine: waves 1..3 into wave 0 (elementwise; lsum per-lane partial) ----
  for (int s = 1; s < 4; s++) {
    if (wave == s) {
#pragma unroll
      for (int vt = 0; vt < 8; vt++) Comb[vt][lane] = acc[vt];
      CombL[lane] = lsum;
    }
    __syncthreads();
    if (wave == 0) {
#pragma unroll
      for (int vt = 0; vt < 8; vt++) {
        f32x4 c = Comb[vt][lane];
        acc[vt] += c;
      }
      lsum += CombL[lane];
    }
    __syncthreads();
  }

  // ---- normalize + pack attn B-frags (wave 0), broadcast via LDS ----
  if (wave == 0) {
    lsum += __shfl_xor(lsum, 16);
    lsum += __shfl_xor(lsum, 32);
    float rinv = 1.0f / lsum;                 // acc cols are all nq = l15: no bcast needed
#pragma unroll
    for (int kc = 0; kc < 4; kc++) {
      short8 t;
#pragma unroll
      for (int r = 0; r < 4; r++) {
        t[r] = (short)f2b(acc[2 * kc][r] * rinv);
        t[r + 4] = (short)f2b(acc[2 * kc + 1][r] * rinv);
      }
      BC[lane][kc] = t;
    }
  }
  __syncthreads();

  // ---- Wo GEMM split across waves (wave w -> oc tiles w*4..w*4+3) + epilogue ----
  short8 bfr[4];
#pragma unroll
  for (int kc = 0; kc < 4; kc++) bfr[kc] = BC[lane][kc];

  f32x4 oacc[4];
#pragma unroll
  for (int mti = 0; mti < 4; mti++) oacc[mti] = (f32x4){0.f, 0.f, 0.f, 0.f};
#pragma unroll
  for (int mti = 0; mti < 4; mti++) {
    int mt = wave * 4 + mti;
#pragma unroll
    for (int kc = 0; kc < 4; kc++) {
      short8 wf = *(const short8*)(Wob + (size_t)(mt * 16 + l15) * 128 + kc * 32 + quad * 8);
      oacc[mti] = __builtin_amdgcn_mfma_f32_16x16x32_bf16(wf, bfr[kc], oacc[mti], 0, 0, 0);
    }
  }
  float gamma = *gammap;
#pragma unroll
  for (int mti = 0; mti < 4; mti++) {
#pragma unroll
    for (int r = 0; r < 4; r++) {
      int oc = (wave * 4 + mti) * 16 + quad * 4 + r;
      size_t idx = ((size_t)b * CHN + oc) * NSEQ + n0 + l15;
      out[idx] = gamma * oacc[mti][r] + x[idx];
    }
  }
}

extern "C" void kernel_launch(void* const* d_in, const int* in_sizes, int n_in,
                              void* d_out, int out_size, void* d_ws, size_t ws_size,
                              hipStream_t stream) {
  const float* x  = (const float*)d_in[0];
  const float* Wt = (const float*)d_in[1];
  const float* Wp = (const float*)d_in[2];
  const float* Wg = (const float*)d_in[3];
  const float* Wo = (const float*)d_in[4];
  const float* gm = (const float*)d_in[5];
  float* out = (float*)d_out;
  u16* ws = (u16*)d_ws;
  u16* QbH  = ws + QH_OFF;
  u16* QbL  = ws + QL_OFF;
  u16* KbH  = ws + KH_OFF;
  u16* KbL  = ws + KL_OFF;
  u16* Vb   = ws + V_OFF;
  u16* Wqkh = ws + WQKH_OFF;
  u16* Wqkl = ws + WQKL_OFF;
  u16* Wgb  = ws + WG_OFF;
  u16* Wob  = ws + WO_OFF;

  prep_weights<<<80, 256, 0, stream>>>(Wt, Wp, Wg, Wo, Wqkh, Wqkl, Wgb, Wob);
  proj_qkv<<<1024, 256, 0, stream>>>(x, Wqkh, Wqkl, Wgb, QbH, QbL, KbH, KbL, Vb);
  flash_attn<<<1024, 256, 0, stream>>>(QbH, QbL, KbH, KbL, Vb, Wob, x, gm, out);
}

// Round 6
// 175.147 us; speedup vs baseline: 1.4119x; 1.4119x over previous
//
#include <hip/hip_runtime.h>

#define NSEQ 4096
#define CHN 256

typedef __attribute__((ext_vector_type(8))) short short8;
typedef __attribute__((ext_vector_type(4))) float f32x4;
typedef __attribute__((ext_vector_type(4))) unsigned short us4;
typedef unsigned short u16;

// fp32 -> bf16 round-to-nearest-even
__device__ __forceinline__ u16 f2b(float f) {
  unsigned u = __builtin_bit_cast(unsigned, f);
  unsigned r = (u + 0x7fffu + ((u >> 16) & 1u)) >> 16;
  return (u16)r;
}
__device__ __forceinline__ float b2f(u16 h) {
  unsigned u = ((unsigned)h) << 16;
  return __builtin_bit_cast(float, u);
}

// ws layout in u16 elements
#define QH_OFF   0u          // [B][N][32]  theta^T hi (pre-scaled by log2e)
#define QL_OFF   524288u     // [B][N][32]  theta^T lo
#define KH_OFF   1048576u    // [B][N][32]  phi^T hi
#define KL_OFF   1572864u    // [B][N][32]  phi^T lo
#define V_OFF    2097152u    // [B][128][N] g
#define WQKH_OFF 4194304u    // [64][256]   (Wt*log2e | Wp) hi
#define WQKL_OFF 4210688u    // [64][256]   (Wt*log2e | Wp) lo
#define WG_OFF   4227072u    // [128][256]  Wg
#define WO_OFF   4259840u    // [256][128]  Wo

// ---------------- kernel 0: weight prep (fp32 -> bf16 / hi+lo) ----------------
__global__ __launch_bounds__(256) void prep_weights(
    const float* __restrict__ Wt, const float* __restrict__ Wp,
    const float* __restrict__ Wg, const float* __restrict__ Wo,
    u16* __restrict__ Wqkh, u16* __restrict__ Wqkl,
    u16* __restrict__ Wgb, u16* __restrict__ Wob) {
  int gid = blockIdx.x * 256 + threadIdx.x;  // 80 blocks -> 20480 threads
  if (gid < 4096) {                          // 64*256/4 float4 tasks, hi/lo split
    int row = gid >> 6;
    int c = (gid & 63) * 4;
    const float* src;
    float scale = 1.0f;
    if (row < 32) { src = Wt + row * 256; scale = 1.44269504088896340736f; }
    else          { src = Wp + (row - 32) * 256; }
    float4 v = *(const float4*)(src + c);
    float w0 = v.x * scale, w1 = v.y * scale, w2 = v.z * scale, w3 = v.w * scale;
    us4 hi = { f2b(w0), f2b(w1), f2b(w2), f2b(w3) };
    us4 lo = { f2b(w0 - b2f(hi[0])), f2b(w1 - b2f(hi[1])),
               f2b(w2 - b2f(hi[2])), f2b(w3 - b2f(hi[3])) };
    *(us4*)(Wqkh + row * 256 + c) = hi;
    *(us4*)(Wqkl + row * 256 + c) = lo;
  } else if (gid < 12288) {                  // Wg: 128*256/4 float4 tasks
    int g = (gid - 4096) * 4;
    float4 v = *(const float4*)(Wg + g);
    us4 o = { f2b(v.x), f2b(v.y), f2b(v.z), f2b(v.w) };
    *(us4*)(Wgb + g) = o;
  } else {                                   // Wo: 256*128/4 float4 tasks
    int g = (gid - 12288) * 4;
    float4 v = *(const float4*)(Wo + g);
    us4 o = { f2b(v.x), f2b(v.y), f2b(v.z), f2b(v.w) };
    *(us4*)(Wob + g) = o;
  }
}

// ---------------- kernel 1: QKV projection, 4-way output-slice split ----------------
// (frozen from round 3/4 — controlled variable; counters next round)
__global__ __launch_bounds__(256, 4) void proj_qkv(
    const float* __restrict__ x,
    const u16* __restrict__ Wqkh, const u16* __restrict__ Wqkl,
    const u16* __restrict__ Wgb,
    u16* __restrict__ QbH, u16* __restrict__ QbL,
    u16* __restrict__ KbH, u16* __restrict__ KbL,
    u16* __restrict__ Vb) {
  int tid = threadIdx.x;
  int wave = tid >> 6, lane = tid & 63;
  int l15 = lane & 15, quad = lane >> 4;
  int slice = blockIdx.x >> 8;
  int tb = blockIdx.x & 255;
  int b = tb >> 6;
  int n0 = (tb & 63) * 64;
  int pos = n0 + wave * 16 + l15;
  const float* xb = x + (size_t)b * CHN * NSEQ + pos;
  int nbase = n0 + wave * 16 + quad * 4;

  if (slice < 2) {
    const u16* Wh = Wqkh + slice * 32 * 256;
    const u16* Wl = Wqkl + slice * 32 * 256;
    f32x4 acc[2];
    acc[0] = (f32x4){0.f, 0.f, 0.f, 0.f};
    acc[1] = (f32x4){0.f, 0.f, 0.f, 0.f};
#pragma unroll
    for (int kc = 0; kc < 8; kc++) {
      short8 ahi, alo;
#pragma unroll
      for (int j = 0; j < 8; j++) {
        float xv = xb[(size_t)(kc * 32 + quad * 8 + j) * NSEQ];
        u16 hi = f2b(xv);
        ahi[j] = (short)hi;
        alo[j] = (short)f2b(xv - b2f(hi));
      }
#pragma unroll
      for (int ot = 0; ot < 2; ot++) {
        size_t off = (size_t)(ot * 16 + l15) * 256 + kc * 32 + quad * 8;
        short8 bh = *(const short8*)(Wh + off);
        short8 bl = *(const short8*)(Wl + off);
        acc[ot] = __builtin_amdgcn_mfma_f32_16x16x32_bf16(alo, bh, acc[ot], 0, 0, 0);
        acc[ot] = __builtin_amdgcn_mfma_f32_16x16x32_bf16(ahi, bl, acc[ot], 0, 0, 0);
        acc[ot] = __builtin_amdgcn_mfma_f32_16x16x32_bf16(ahi, bh, acc[ot], 0, 0, 0);
      }
    }
    u16* Hp = (slice == 0) ? QbH : KbH;
    u16* Lp = (slice == 0) ? QbL : KbL;
#pragma unroll
    for (int ot = 0; ot < 2; ot++) {
#pragma unroll
      for (int r = 0; r < 4; r++) {
        float v = acc[ot][r];
        u16 hi = f2b(v);
        u16 lo = f2b(v - b2f(hi));
        size_t nrow = (size_t)(b * NSEQ + nbase + r) * 32 + ot * 16 + l15;
        Hp[nrow] = hi; Lp[nrow] = lo;
      }
    }
  } else {
    const u16* Wg2 = Wgb + (size_t)(slice - 2) * 64 * 256;
    f32x4 acc[4];
#pragma unroll
    for (int oi = 0; oi < 4; oi++) acc[oi] = (f32x4){0.f, 0.f, 0.f, 0.f};
#pragma unroll
    for (int kc = 0; kc < 8; kc++) {
      short8 ahi;
#pragma unroll
      for (int j = 0; j < 8; j++)
        ahi[j] = (short)f2b(xb[(size_t)(kc * 32 + quad * 8 + j) * NSEQ]);
#pragma unroll
      for (int oi = 0; oi < 4; oi++) {
        short8 bg = *(const short8*)(Wg2 + (size_t)(oi * 16 + l15) * 256 + kc * 32 + quad * 8);
        acc[oi] = __builtin_amdgcn_mfma_f32_16x16x32_bf16(ahi, bg, acc[oi], 0, 0, 0);
      }
    }
#pragma unroll
    for (int oi = 0; oi < 4; oi++) {
      int c = (slice - 2) * 64 + oi * 16 + l15;
      us4 pk = { f2b(acc[oi][0]), f2b(acc[oi][1]), f2b(acc[oi][2]), f2b(acc[oi][3]) };
      *(us4*)(Vb + (size_t)(b * 128 + c) * NSEQ + nbase) = pk;
    }
  }
}

// ---------------- kernel 2: fused flash attention + Wo + epilogue (v4) ----------------
// 512 threads: 8 waves = 4 key-splits x 2 row-groups; 2 Q-tiles (32 rows) per wave;
// register-only main loop (key-row permutation chains QK^T->PV->Wo layouts);
// phase-rotated K-loop start per tile to de-synchronize L2 address streams.
// grid 256 = 4 batches x 64 row-tiles = 1 block/CU, 8 waves/CU.
__global__ __launch_bounds__(512, 2) void flash_attn(
    const u16* __restrict__ QbH, const u16* __restrict__ QbL,
    const u16* __restrict__ KbH, const u16* __restrict__ KbL,
    const u16* __restrict__ Vb, const u16* __restrict__ Wob,
    const float* __restrict__ x, const float* __restrict__ gammap,
    float* __restrict__ out) {
  // smem map: CombA @0 (32KB, aliased later by BC 20.5KB), CombB @32768 (32KB),
  //           CombLA @65536 (1KB), CombLB @66560 (1KB)
  __shared__ alignas(16) char smem[67584];
  f32x4 (*CombA)[16][64] = (f32x4(*)[16][64])smem;
  f32x4 (*CombB)[16][64] = (f32x4(*)[16][64])(smem + 32768);
  float (*CombLA)[2][64] = (float(*)[2][64])(smem + 65536);
  float (*CombLB)[2][64] = (float(*)[2][64])(smem + 66560);
  u16* BC = (u16*)smem;   // [4 nqt][64 lanes][40]  (80 B lane stride, 16B-aligned)

  int tid = threadIdx.x;
  int wave = tid >> 6, lane = tid & 63;
  int l15 = lane & 15, quad = lane >> 4;
  int sp = wave >> 1, rg = wave & 1;
  int b = blockIdx.x & 3;
  int tile = blockIdx.x >> 2;
  int n0 = tile * 64;
  int nqb = n0 + rg * 32;
  int ms = sp * 1024;                       // this split's key base
  int phase = tile & 31;                    // de-synchronized chunk start
  int rk = ((l15 >> 2) << 3) + (l15 & 3);   // permuted row-in-tile

  short8 qh[2], ql[2];
#pragma unroll
  for (int nt = 0; nt < 2; nt++) {
    size_t qoff = (size_t)(b * NSEQ + nqb + nt * 16 + l15) * 32 + quad * 8;
    qh[nt] = *(const short8*)(QbH + qoff);
    ql[nt] = *(const short8*)(QbL + qoff);
  }
  const u16* KpH = KbH + (size_t)b * NSEQ * 32 + (size_t)(ms + rk) * 32 + quad * 8;
  const u16* KpL = KbL + (size_t)b * NSEQ * 32 + (size_t)(ms + rk) * 32 + quad * 8;
  const u16* Vp  = Vb + (size_t)b * 128 * NSEQ + (size_t)rk * NSEQ + ms + quad * 8;

  f32x4 acc[2][8];
#pragma unroll
  for (int nt = 0; nt < 2; nt++)
#pragma unroll
    for (int vt = 0; vt < 8; vt++) acc[nt][vt] = (f32x4){0.f, 0.f, 0.f, 0.f};
  float lsum[2] = {0.f, 0.f};

  // prefetch chunk 'phase'
  short8 kh0 = *(const short8*)(KpH + (size_t)phase * 1024);
  short8 kh1 = *(const short8*)(KpH + (size_t)phase * 1024 + 128);
  short8 kl0 = *(const short8*)(KpL + (size_t)phase * 1024);
  short8 kl1 = *(const short8*)(KpL + (size_t)phase * 1024 + 128);
  short8 vf[8];
#pragma unroll
  for (int vt = 0; vt < 8; vt++)
    vf[vt] = *(const short8*)(Vp + (size_t)((vt >> 1) * 32 + (vt & 1) * 4) * NSEQ + phase * 32);

  for (int ci = 0; ci < 32; ci++) {
    int cn = (phase + ci + 1) & 31;         // next chunk (wraps harmlessly)
    short8 nkh0 = *(const short8*)(KpH + (size_t)cn * 1024);
    short8 nkh1 = *(const short8*)(KpH + (size_t)cn * 1024 + 128);
    short8 nkl0 = *(const short8*)(KpL + (size_t)cn * 1024);
    short8 nkl1 = *(const short8*)(KpL + (size_t)cn * 1024 + 128);
    short8 nvf[8];
#pragma unroll
    for (int vt = 0; vt < 8; vt++)
      nvf[vt] = *(const short8*)(Vp + (size_t)((vt >> 1) * 32 + (vt & 1) * 4) * NSEQ + cn * 32);

#pragma unroll
    for (int nt = 0; nt < 2; nt++) {
      // S^T over permuted keys; hi/lo split, small terms first.
      f32x4 z = (f32x4){0.f, 0.f, 0.f, 0.f};
      f32x4 s0 = __builtin_amdgcn_mfma_f32_16x16x32_bf16(kl0, qh[nt], z, 0, 0, 0);
      s0 = __builtin_amdgcn_mfma_f32_16x16x32_bf16(kh0, ql[nt], s0, 0, 0, 0);
      s0 = __builtin_amdgcn_mfma_f32_16x16x32_bf16(kh0, qh[nt], s0, 0, 0, 0);
      f32x4 s1 = __builtin_amdgcn_mfma_f32_16x16x32_bf16(kl1, qh[nt], z, 0, 0, 0);
      s1 = __builtin_amdgcn_mfma_f32_16x16x32_bf16(kh1, ql[nt], s1, 0, 0, 0);
      s1 = __builtin_amdgcn_mfma_f32_16x16x32_bf16(kh1, qh[nt], s1, 0, 0, 0);

      // exp2 -> packed short8 == B-frag of PV (k = quad*8 + j)
      short8 pp;
#pragma unroll
      for (int r = 0; r < 4; r++) {
        float e0 = exp2f(s0[r]);
        float e1 = exp2f(s1[r]);
        lsum[nt] += e0 + e1;
        pp[r] = (short)f2b(e0);
        pp[r + 4] = (short)f2b(e1);
      }
#pragma unroll
      for (int vt = 0; vt < 8; vt++)
        acc[nt][vt] = __builtin_amdgcn_mfma_f32_16x16x32_bf16(vf[vt], pp, acc[nt][vt], 0, 0, 0);
    }

    kh0 = nkh0; kh1 = nkh1; kl0 = nkl0; kl1 = nkl1;
#pragma unroll
    for (int vt = 0; vt < 8; vt++) vf[vt] = nvf[vt];
  }

  // ---- split-K tree combine: (sp2->sp0, sp3->sp1), then sp1->sp0 ----
  if (sp == 2) {
#pragma unroll
    for (int nt = 0; nt < 2; nt++) {
#pragma unroll
      for (int vt = 0; vt < 8; vt++) CombA[rg][nt * 8 + vt][lane] = acc[nt][vt];
      CombLA[rg][nt][lane] = lsum[nt];
    }
  } else if (sp == 3) {
#pragma unroll
    for (int nt = 0; nt < 2; nt++) {
#pragma unroll
      for (int vt = 0; vt < 8; vt++) CombB[rg][nt * 8 + vt][lane] = acc[nt][vt];
      CombLB[rg][nt][lane] = lsum[nt];
    }
  }
  __syncthreads();
  if (sp == 0) {
#pragma unroll
    for (int nt = 0; nt < 2; nt++) {
#pragma unroll
      for (int vt = 0; vt < 8; vt++) acc[nt][vt] += CombA[rg][nt * 8 + vt][lane];
      lsum[nt] += CombLA[rg][nt][lane];
    }
  } else if (sp == 1) {
#pragma unroll
    for (int nt = 0; nt < 2; nt++) {
#pragma unroll
      for (int vt = 0; vt < 8; vt++) acc[nt][vt] += CombB[rg][nt * 8 + vt][lane];
      lsum[nt] += CombLB[rg][nt][lane];
    }
  }
  __syncthreads();
  if (sp == 1) {
#pragma unroll
    for (int nt = 0; nt < 2; nt++) {
#pragma unroll
      for (int vt = 0; vt < 8; vt++) CombA[rg][nt * 8 + vt][lane] = acc[nt][vt];
      CombLA[rg][nt][lane] = lsum[nt];
    }
  }
  __syncthreads();
  if (sp == 0) {
#pragma unroll
    for (int nt = 0; nt < 2; nt++) {
#pragma unroll
      for (int vt = 0; vt < 8; vt++) acc[nt][vt] += CombA[rg][nt * 8 + vt][lane];
      lsum[nt] += CombLA[rg][nt][lane];
    }
    // ---- normalize + pack attn B-frags into BC (aliases CombA; safe post-barrier) ----
#pragma unroll
    for (int nt = 0; nt < 2; nt++) {
      lsum[nt] += __shfl_xor(lsum[nt], 16);
      lsum[nt] += __shfl_xor(lsum[nt], 32);
      float rinv = 1.0f / lsum[nt];          // acc cols all nq = l15: no bcast needed
      int nqt = rg * 2 + nt;
#pragma unroll
      for (int kc = 0; kc < 4; kc++) {
        short8 t;
#pragma unroll
        for (int r = 0; r < 4; r++) {
          t[r]     = (short)f2b(acc[nt][2 * kc][r] * rinv);
          t[r + 4] = (short)f2b(acc[nt][2 * kc + 1][r] * rinv);
        }
        *(short8*)&BC[(size_t)(nqt * 64 + lane) * 40 + kc * 8] = t;
      }
    }
  }
  __syncthreads();

  // ---- Wo GEMM + epilogue across all 8 waves: wave w -> oc-tiles 2w, 2w+1 ----
  short8 bfr[4][4];
#pragma unroll
  for (int nqt = 0; nqt < 4; nqt++)
#pragma unroll
    for (int kc = 0; kc < 4; kc++)
      bfr[nqt][kc] = *(const short8*)&BC[(size_t)(nqt * 64 + lane) * 40 + kc * 8];

  float gamma = *gammap;
#pragma unroll
  for (int mti = 0; mti < 2; mti++) {
    int mt = wave * 2 + mti;
    short8 wf[4];
#pragma unroll
    for (int kc = 0; kc < 4; kc++)
      wf[kc] = *(const short8*)(Wob + (size_t)(mt * 16 + l15) * 128 + kc * 32 + quad * 8);
#pragma unroll
    for (int nqt = 0; nqt < 4; nqt++) {
      f32x4 oacc = (f32x4){0.f, 0.f, 0.f, 0.f};
#pragma unroll
      for (int kc = 0; kc < 4; kc++)
        oacc = __builtin_amdgcn_mfma_f32_16x16x32_bf16(wf[kc], bfr[nqt][kc], oacc, 0, 0, 0);
#pragma unroll
      for (int r = 0; r < 4; r++) {
        int oc = mt * 16 + quad * 4 + r;
        size_t idx = ((size_t)b * CHN + oc) * NSEQ + n0 + nqt * 16 + l15;
        out[idx] = gamma * oacc[r] + x[idx];
      }
    }
  }
}

extern "C" void kernel_launch(void* const* d_in, const int* in_sizes, int n_in,
                              void* d_out, int out_size, void* d_ws, size_t ws_size,
                              hipStream_t stream) {
  const float* x  = (const float*)d_in[0];
  const float* Wt = (const float*)d_in[1];
  const float* Wp = (const float*)d_in[2];
  const float* Wg = (const float*)d_in[3];
  const float* Wo = (const float*)d_in[4];
  const float* gm = (const float*)d_in[5];
  float* out = (float*)d_out;
  u16* ws = (u16*)d_ws;
  u16* QbH  = ws + QH_OFF;
  u16* QbL  = ws + QL_OFF;
  u16* KbH  = ws + KH_OFF;
  u16* KbL  = ws + KL_OFF;
  u16* Vb   = ws + V_OFF;
  u16* Wqkh = ws + WQKH_OFF;
  u16* Wqkl = ws + WQKL_OFF;
  u16* Wgb  = ws + WG_OFF;
  u16* Wob  = ws + WO_OFF;

  prep_weights<<<80, 256, 0, stream>>>(Wt, Wp, Wg, Wo, Wqkh, Wqkl, Wgb, Wob);
  proj_qkv<<<1024, 256, 0, stream>>>(x, Wqkh, Wqkl, Wgb, QbH, QbL, KbH, KbL, Vb);
  flash_attn<<<256, 512, 0, stream>>>(QbH, QbL, KbH, KbL, Vb, Wob, x, gm, out);
}

// Round 7
// 174.546 us; speedup vs baseline: 1.4167x; 1.0034x over previous
//
#include <hip/hip_runtime.h>

#define NSEQ 4096
#define CHN 256
#define VLD 4160   // padded V leading dim (8320 B row stride = 2^7 * 65 -> breaks L2 channel aliasing)

typedef __attribute__((ext_vector_type(8))) short short8;
typedef __attribute__((ext_vector_type(4))) float f32x4;
typedef __attribute__((ext_vector_type(4))) unsigned short us4;
typedef unsigned short u16;

// fp32 -> bf16 round-to-nearest-even
__device__ __forceinline__ u16 f2b(float f) {
  unsigned u = __builtin_bit_cast(unsigned, f);
  unsigned r = (u + 0x7fffu + ((u >> 16) & 1u)) >> 16;
  return (u16)r;
}
__device__ __forceinline__ float b2f(u16 h) {
  unsigned u = ((unsigned)h) << 16;
  return __builtin_bit_cast(float, u);
}

// ws layout in u16 elements
#define QH_OFF   0u          // [B][N][32]    theta^T hi (pre-scaled by log2e)
#define QL_OFF   524288u     // [B][N][32]    theta^T lo
#define KH_OFF   1048576u    // [B][N][32]    phi^T hi
#define KL_OFF   1572864u    // [B][N][32]    phi^T lo
#define V_OFF    2097152u    // [B][128][VLD] g (padded rows)
#define WQKH_OFF 4227072u    // [64][256]     (Wt*log2e | Wp) hi
#define WQKL_OFF 4243456u    // [64][256]     (Wt*log2e | Wp) lo
#define WG_OFF   4259840u    // [128][256]    Wg
#define WO_OFF   4292608u    // [256][128]    Wo

// ---------------- kernel 0: weight prep (fp32 -> bf16 / hi+lo) ----------------
__global__ __launch_bounds__(256) void prep_weights(
    const float* __restrict__ Wt, const float* __restrict__ Wp,
    const float* __restrict__ Wg, const float* __restrict__ Wo,
    u16* __restrict__ Wqkh, u16* __restrict__ Wqkl,
    u16* __restrict__ Wgb, u16* __restrict__ Wob) {
  int gid = blockIdx.x * 256 + threadIdx.x;  // 80 blocks -> 20480 threads
  if (gid < 4096) {                          // 64*256/4 float4 tasks, hi/lo split
    int row = gid >> 6;
    int c = (gid & 63) * 4;
    const float* src;
    float scale = 1.0f;
    if (row < 32) { src = Wt + row * 256; scale = 1.44269504088896340736f; }
    else          { src = Wp + (row - 32) * 256; }
    float4 v = *(const float4*)(src + c);
    float w0 = v.x * scale, w1 = v.y * scale, w2 = v.z * scale, w3 = v.w * scale;
    us4 hi = { f2b(w0), f2b(w1), f2b(w2), f2b(w3) };
    us4 lo = { f2b(w0 - b2f(hi[0])), f2b(w1 - b2f(hi[1])),
               f2b(w2 - b2f(hi[2])), f2b(w3 - b2f(hi[3])) };
    *(us4*)(Wqkh + row * 256 + c) = hi;
    *(us4*)(Wqkl + row * 256 + c) = lo;
  } else if (gid < 12288) {                  // Wg: 128*256/4 float4 tasks
    int g = (gid - 4096) * 4;
    float4 v = *(const float4*)(Wg + g);
    us4 o = { f2b(v.x), f2b(v.y), f2b(v.z), f2b(v.w) };
    *(us4*)(Wgb + g) = o;
  } else {                                   // Wo: 256*128/4 float4 tasks
    int g = (gid - 12288) * 4;
    float4 v = *(const float4*)(Wo + g);
    us4 o = { f2b(v.x), f2b(v.y), f2b(v.z), f2b(v.w) };
    *(us4*)(Wob + g) = o;
  }
}

// ---------------- kernel 1: QKV projection, 4-way output-slice split ----------------
// (frozen except V store stride -> VLD)
__global__ __launch_bounds__(256, 4) void proj_qkv(
    const float* __restrict__ x,
    const u16* __restrict__ Wqkh, const u16* __restrict__ Wqkl,
    const u16* __restrict__ Wgb,
    u16* __restrict__ QbH, u16* __restrict__ QbL,
    u16* __restrict__ KbH, u16* __restrict__ KbL,
    u16* __restrict__ Vb) {
  int tid = threadIdx.x;
  int wave = tid >> 6, lane = tid & 63;
  int l15 = lane & 15, quad = lane >> 4;
  int slice = blockIdx.x >> 8;
  int tb = blockIdx.x & 255;
  int b = tb >> 6;
  int n0 = (tb & 63) * 64;
  int pos = n0 + wave * 16 + l15;
  const float* xb = x + (size_t)b * CHN * NSEQ + pos;
  int nbase = n0 + wave * 16 + quad * 4;

  if (slice < 2) {
    const u16* Wh = Wqkh + slice * 32 * 256;
    const u16* Wl = Wqkl + slice * 32 * 256;
    f32x4 acc[2];
    acc[0] = (f32x4){0.f, 0.f, 0.f, 0.f};
    acc[1] = (f32x4){0.f, 0.f, 0.f, 0.f};
#pragma unroll
    for (int kc = 0; kc < 8; kc++) {
      short8 ahi, alo;
#pragma unroll
      for (int j = 0; j < 8; j++) {
        float xv = xb[(size_t)(kc * 32 + quad * 8 + j) * NSEQ];
        u16 hi = f2b(xv);
        ahi[j] = (short)hi;
        alo[j] = (short)f2b(xv - b2f(hi));
      }
#pragma unroll
      for (int ot = 0; ot < 2; ot++) {
        size_t off = (size_t)(ot * 16 + l15) * 256 + kc * 32 + quad * 8;
        short8 bh = *(const short8*)(Wh + off);
        short8 bl = *(const short8*)(Wl + off);
        acc[ot] = __builtin_amdgcn_mfma_f32_16x16x32_bf16(alo, bh, acc[ot], 0, 0, 0);
        acc[ot] = __builtin_amdgcn_mfma_f32_16x16x32_bf16(ahi, bl, acc[ot], 0, 0, 0);
        acc[ot] = __builtin_amdgcn_mfma_f32_16x16x32_bf16(ahi, bh, acc[ot], 0, 0, 0);
      }
    }
    u16* Hp = (slice == 0) ? QbH : KbH;
    u16* Lp = (slice == 0) ? QbL : KbL;
#pragma unroll
    for (int ot = 0; ot < 2; ot++) {
#pragma unroll
      for (int r = 0; r < 4; r++) {
        float v = acc[ot][r];
        u16 hi = f2b(v);
        u16 lo = f2b(v - b2f(hi));
        size_t nrow = (size_t)(b * NSEQ + nbase + r) * 32 + ot * 16 + l15;
        Hp[nrow] = hi; Lp[nrow] = lo;
      }
    }
  } else {
    const u16* Wg2 = Wgb + (size_t)(slice - 2) * 64 * 256;
    f32x4 acc[4];
#pragma unroll
    for (int oi = 0; oi < 4; oi++) acc[oi] = (f32x4){0.f, 0.f, 0.f, 0.f};
#pragma unroll
    for (int kc = 0; kc < 8; kc++) {
      short8 ahi;
#pragma unroll
      for (int j = 0; j < 8; j++)
        ahi[j] = (short)f2b(xb[(size_t)(kc * 32 + quad * 8 + j) * NSEQ]);
#pragma unroll
      for (int oi = 0; oi < 4; oi++) {
        short8 bg = *(const short8*)(Wg2 + (size_t)(oi * 16 + l15) * 256 + kc * 32 + quad * 8);
        acc[oi] = __builtin_amdgcn_mfma_f32_16x16x32_bf16(ahi, bg, acc[oi], 0, 0, 0);
      }
    }
#pragma unroll
    for (int oi = 0; oi < 4; oi++) {
      int c = (slice - 2) * 64 + oi * 16 + l15;
      us4 pk = { f2b(acc[oi][0]), f2b(acc[oi][1]), f2b(acc[oi][2]), f2b(acc[oi][3]) };
      *(us4*)(Vb + (size_t)(b * 128 + c) * VLD + nbase) = pk;
    }
  }
}

// ---------------- kernel 2: fused flash attention + Wo + epilogue (v5) ----------------
// v4 + padded V rows (VLD). 512 threads: 8 waves = 4 key-splits x 2 row-groups;
// register-only main loop; phase-rotated K-loop start per tile.
// grid 256 = 4 batches x 64 row-tiles = 1 block/CU, 8 waves/CU.
__global__ __launch_bounds__(512, 2) void flash_attn(
    const u16* __restrict__ QbH, const u16* __restrict__ QbL,
    const u16* __restrict__ KbH, const u16* __restrict__ KbL,
    const u16* __restrict__ Vb, const u16* __restrict__ Wob,
    const float* __restrict__ x, const float* __restrict__ gammap,
    float* __restrict__ out) {
  // smem map: CombA @0 (32KB, aliased later by BC 20.5KB), CombB @32768 (32KB),
  //           CombLA @65536 (1KB), CombLB @66560 (1KB)
  __shared__ alignas(16) char smem[67584];
  f32x4 (*CombA)[16][64] = (f32x4(*)[16][64])smem;
  f32x4 (*CombB)[16][64] = (f32x4(*)[16][64])(smem + 32768);
  float (*CombLA)[2][64] = (float(*)[2][64])(smem + 65536);
  float (*CombLB)[2][64] = (float(*)[2][64])(smem + 66560);
  u16* BC = (u16*)smem;   // [4 nqt][64 lanes][40]  (80 B lane stride, 16B-aligned)

  int tid = threadIdx.x;
  int wave = tid >> 6, lane = tid & 63;
  int l15 = lane & 15, quad = lane >> 4;
  int sp = wave >> 1, rg = wave & 1;
  int b = blockIdx.x & 3;
  int tile = blockIdx.x >> 2;
  int n0 = tile * 64;
  int nqb = n0 + rg * 32;
  int ms = sp * 1024;                       // this split's key base
  int phase = tile & 31;                    // de-synchronized chunk start
  int rk = ((l15 >> 2) << 3) + (l15 & 3);   // permuted row-in-tile

  short8 qh[2], ql[2];
#pragma unroll
  for (int nt = 0; nt < 2; nt++) {
    size_t qoff = (size_t)(b * NSEQ + nqb + nt * 16 + l15) * 32 + quad * 8;
    qh[nt] = *(const short8*)(QbH + qoff);
    ql[nt] = *(const short8*)(QbL + qoff);
  }
  const u16* KpH = KbH + (size_t)b * NSEQ * 32 + (size_t)(ms + rk) * 32 + quad * 8;
  const u16* KpL = KbL + (size_t)b * NSEQ * 32 + (size_t)(ms + rk) * 32 + quad * 8;
  const u16* Vp  = Vb + (size_t)b * 128 * VLD + (size_t)rk * VLD + ms + quad * 8;

  f32x4 acc[2][8];
#pragma unroll
  for (int nt = 0; nt < 2; nt++)
#pragma unroll
    for (int vt = 0; vt < 8; vt++) acc[nt][vt] = (f32x4){0.f, 0.f, 0.f, 0.f};
  float lsum[2] = {0.f, 0.f};

  // prefetch chunk 'phase'
  short8 kh0 = *(const short8*)(KpH + (size_t)phase * 1024);
  short8 kh1 = *(const short8*)(KpH + (size_t)phase * 1024 + 128);
  short8 kl0 = *(const short8*)(KpL + (size_t)phase * 1024);
  short8 kl1 = *(const short8*)(KpL + (size_t)phase * 1024 + 128);
  short8 vf[8];
#pragma unroll
  for (int vt = 0; vt < 8; vt++)
    vf[vt] = *(const short8*)(Vp + (size_t)((vt >> 1) * 32 + (vt & 1) * 4) * VLD + phase * 32);

  for (int ci = 0; ci < 32; ci++) {
    int cn = (phase + ci + 1) & 31;         // next chunk (wraps harmlessly)
    short8 nkh0 = *(const short8*)(KpH + (size_t)cn * 1024);
    short8 nkh1 = *(const short8*)(KpH + (size_t)cn * 1024 + 128);
    short8 nkl0 = *(const short8*)(KpL + (size_t)cn * 1024);
    short8 nkl1 = *(const short8*)(KpL + (size_t)cn * 1024 + 128);
    short8 nvf[8];
#pragma unroll
    for (int vt = 0; vt < 8; vt++)
      nvf[vt] = *(const short8*)(Vp + (size_t)((vt >> 1) * 32 + (vt & 1) * 4) * VLD + cn * 32);

#pragma unroll
    for (int nt = 0; nt < 2; nt++) {
      // S^T over permuted keys; hi/lo split, small terms first.
      f32x4 z = (f32x4){0.f, 0.f, 0.f, 0.f};
      f32x4 s0 = __builtin_amdgcn_mfma_f32_16x16x32_bf16(kl0, qh[nt], z, 0, 0, 0);
      s0 = __builtin_amdgcn_mfma_f32_16x16x32_bf16(kh0, ql[nt], s0, 0, 0, 0);
      s0 = __builtin_amdgcn_mfma_f32_16x16x32_bf16(kh0, qh[nt], s0, 0, 0, 0);
      f32x4 s1 = __builtin_amdgcn_mfma_f32_16x16x32_bf16(kl1, qh[nt], z, 0, 0, 0);
      s1 = __builtin_amdgcn_mfma_f32_16x16x32_bf16(kh1, ql[nt], s1, 0, 0, 0);
      s1 = __builtin_amdgcn_mfma_f32_16x16x32_bf16(kh1, qh[nt], s1, 0, 0, 0);

      // exp2 -> packed short8 == B-frag of PV (k = quad*8 + j)
      short8 pp;
#pragma unroll
      for (int r = 0; r < 4; r++) {
        float e0 = exp2f(s0[r]);
        float e1 = exp2f(s1[r]);
        lsum[nt] += e0 + e1;
        pp[r] = (short)f2b(e0);
        pp[r + 4] = (short)f2b(e1);
      }
#pragma unroll
      for (int vt = 0; vt < 8; vt++)
        acc[nt][vt] = __builtin_amdgcn_mfma_f32_16x16x32_bf16(vf[vt], pp, acc[nt][vt], 0, 0, 0);
    }

    kh0 = nkh0; kh1 = nkh1; kl0 = nkl0; kl1 = nkl1;
#pragma unroll
    for (int vt = 0; vt < 8; vt++) vf[vt] = nvf[vt];
  }

  // ---- split-K tree combine: (sp2->sp0, sp3->sp1), then sp1->sp0 ----
  if (sp == 2) {
#pragma unroll
    for (int nt = 0; nt < 2; nt++) {
#pragma unroll
      for (int vt = 0; vt < 8; vt++) CombA[rg][nt * 8 + vt][lane] = acc[nt][vt];
      CombLA[rg][nt][lane] = lsum[nt];
    }
  } else if (sp == 3) {
#pragma unroll
    for (int nt = 0; nt < 2; nt++) {
#pragma unroll
      for (int vt = 0; vt < 8; vt++) CombB[rg][nt * 8 + vt][lane] = acc[nt][vt];
      CombLB[rg][nt][lane] = lsum[nt];
    }
  }
  __syncthreads();
  if (sp == 0) {
#pragma unroll
    for (int nt = 0; nt < 2; nt++) {
#pragma unroll
      for (int vt = 0; vt < 8; vt++) acc[nt][vt] += CombA[rg][nt * 8 + vt][lane];
      lsum[nt] += CombLA[rg][nt][lane];
    }
  } else if (sp == 1) {
#pragma unroll
    for (int nt = 0; nt < 2; nt++) {
#pragma unroll
      for (int vt = 0; vt < 8; vt++) acc[nt][vt] += CombB[rg][nt * 8 + vt][lane];
      lsum[nt] += CombLB[rg][nt][lane];
    }
  }
  __syncthreads();
  if (sp == 1) {
#pragma unroll
    for (int nt = 0; nt < 2; nt++) {
#pragma unroll
      for (int vt = 0; vt < 8; vt++) CombA[rg][nt * 8 + vt][lane] = acc[nt][vt];
      CombLA[rg][nt][lane] = lsum[nt];
    }
  }
  __syncthreads();
  if (sp == 0) {
#pragma unroll
    for (int nt = 0; nt < 2; nt++) {
#pragma unroll
      for (int vt = 0; vt < 8; vt++) acc[nt][vt] += CombA[rg][nt * 8 + vt][lane];
      lsum[nt] += CombLA[rg][nt][lane];
    }
    // ---- normalize + pack attn B-frags into BC (aliases CombA; safe post-barrier) ----
#pragma unroll
    for (int nt = 0; nt < 2; nt++) {
      lsum[nt] += __shfl_xor(lsum[nt], 16);
      lsum[nt] += __shfl_xor(lsum[nt], 32);
      float rinv = 1.0f / lsum[nt];          // acc cols all nq = l15: no bcast needed
      int nqt = rg * 2 + nt;
#pragma unroll
      for (int kc = 0; kc < 4; kc++) {
        short8 t;
#pragma unroll
        for (int r = 0; r < 4; r++) {
          t[r]     = (short)f2b(acc[nt][2 * kc][r] * rinv);
          t[r + 4] = (short)f2b(acc[nt][2 * kc + 1][r] * rinv);
        }
        *(short8*)&BC[(size_t)(nqt * 64 + lane) * 40 + kc * 8] = t;
      }
    }
  }
  __syncthreads();

  // ---- Wo GEMM + epilogue across all 8 waves: wave w -> oc-tiles 2w, 2w+1 ----
  short8 bfr[4][4];
#pragma unroll
  for (int nqt = 0; nqt < 4; nqt++)
#pragma unroll
    for (int kc = 0; kc < 4; kc++)
      bfr[nqt][kc] = *(const short8*)&BC[(size_t)(nqt * 64 + lane) * 40 + kc * 8];

  float gamma = *gammap;
#pragma unroll
  for (int mti = 0; mti < 2; mti++) {
    int mt = wave * 2 + mti;
    short8 wf[4];
#pragma unroll
    for (int kc = 0; kc < 4; kc++)
      wf[kc] = *(const short8*)(Wob + (size_t)(mt * 16 + l15) * 128 + kc * 32 + quad * 8);
#pragma unroll
    for (int nqt = 0; nqt < 4; nqt++) {
      f32x4 oacc = (f32x4){0.f, 0.f, 0.f, 0.f};
#pragma unroll
      for (int kc = 0; kc < 4; kc++)
        oacc = __builtin_amdgcn_mfma_f32_16x16x32_bf16(wf[kc], bfr[nqt][kc], oacc, 0, 0, 0);
#pragma unroll
      for (int r = 0; r < 4; r++) {
        int oc = mt * 16 + quad * 4 + r;
        size_t idx = ((size_t)b * CHN + oc) * NSEQ + n0 + nqt * 16 + l15;
        out[idx] = gamma * oacc[r] + x[idx];
      }
    }
  }
}

extern "C" void kernel_launch(void* const* d_in, const int* in_sizes, int n_in,
                              void* d_out, int out_size, void* d_ws, size_t ws_size,
                              hipStream_t stream) {
  const float* x  = (const float*)d_in[0];
  const float* Wt = (const float*)d_in[1];
  const float* Wp = (const float*)d_in[2];
  const float* Wg = (const float*)d_in[3];
  const float* Wo = (const float*)d_in[4];
  const float* gm = (const float*)d_in[5];
  float* out = (float*)d_out;
  u16* ws = (u16*)d_ws;
  u16* QbH  = ws + QH_OFF;
  u16* QbL  = ws + QL_OFF;
  u16* KbH  = ws + KH_OFF;
  u16* KbL  = ws + KL_OFF;
  u16* Vb   = ws + V_OFF;
  u16* Wqkh = ws + WQKH_OFF;
  u16* Wqkl = ws + WQKL_OFF;
  u16* Wgb  = ws + WG_OFF;
  u16* Wob  = ws + WO_OFF;

  prep_weights<<<80, 256, 0, stream>>>(Wt, Wp, Wg, Wo, Wqkh, Wqkl, Wgb, Wob);
  proj_qkv<<<1024, 256, 0, stream>>>(x, Wqkh, Wqkl, Wgb, QbH, QbL, KbH, KbL, Vb);
  flash_attn<<<256, 512, 0, stream>>>(QbH, QbL, KbH, KbL, Vb, Wob, x, gm, out);
}

// Round 8
// 174.080 us; speedup vs baseline: 1.4205x; 1.0027x over previous
//
#include <hip/hip_runtime.h>

#define NSEQ 4096
#define CHN 256
#define VLD 4160   // padded V leading dim (kept from v5; harmless)

typedef __attribute__((ext_vector_type(8))) short short8;
typedef __attribute__((ext_vector_type(4))) float f32x4;
typedef __attribute__((ext_vector_type(4))) unsigned short us4;
typedef unsigned short u16;

// fp32 -> bf16 round-to-nearest-even
__device__ __forceinline__ u16 f2b(float f) {
  unsigned u = __builtin_bit_cast(unsigned, f);
  unsigned r = (u + 0x7fffu + ((u >> 16) & 1u)) >> 16;
  return (u16)r;
}
__device__ __forceinline__ float b2f(u16 h) {
  unsigned u = ((unsigned)h) << 16;
  return __builtin_bit_cast(float, u);
}

// ws layout in u16 elements
#define QH_OFF   0u          // [B][N][32]    theta^T hi (pre-scaled by log2e)
#define QL_OFF   524288u     // [B][N][32]    theta^T lo
#define KH_OFF   1048576u    // [B][N][32]    phi^T hi
#define KL_OFF   1572864u    // [B][N][32]    phi^T lo
#define V_OFF    2097152u    // [B][128][VLD] g (padded rows)
#define WQKH_OFF 4227072u    // [64][256]     (Wt*log2e | Wp) hi
#define WQKL_OFF 4243456u    // [64][256]     (Wt*log2e | Wp) lo
#define WG_OFF   4259840u    // [128][256]    Wg
#define WO_OFF   4292608u    // [256][128]    Wo

// ---------------- kernel 0: weight prep (fp32 -> bf16 / hi+lo) ----------------
__global__ __launch_bounds__(256) void prep_weights(
    const float* __restrict__ Wt, const float* __restrict__ Wp,
    const float* __restrict__ Wg, const float* __restrict__ Wo,
    u16* __restrict__ Wqkh, u16* __restrict__ Wqkl,
    u16* __restrict__ Wgb, u16* __restrict__ Wob) {
  int gid = blockIdx.x * 256 + threadIdx.x;  // 80 blocks -> 20480 threads
  if (gid < 4096) {                          // 64*256/4 float4 tasks, hi/lo split
    int row = gid >> 6;
    int c = (gid & 63) * 4;
    const float* src;
    float scale = 1.0f;
    if (row < 32) { src = Wt + row * 256; scale = 1.44269504088896340736f; }
    else          { src = Wp + (row - 32) * 256; }
    float4 v = *(const float4*)(src + c);
    float w0 = v.x * scale, w1 = v.y * scale, w2 = v.z * scale, w3 = v.w * scale;
    us4 hi = { f2b(w0), f2b(w1), f2b(w2), f2b(w3) };
    us4 lo = { f2b(w0 - b2f(hi[0])), f2b(w1 - b2f(hi[1])),
               f2b(w2 - b2f(hi[2])), f2b(w3 - b2f(hi[3])) };
    *(us4*)(Wqkh + row * 256 + c) = hi;
    *(us4*)(Wqkl + row * 256 + c) = lo;
  } else if (gid < 12288) {                  // Wg: 128*256/4 float4 tasks
    int g = (gid - 4096) * 4;
    float4 v = *(const float4*)(Wg + g);
    us4 o = { f2b(v.x), f2b(v.y), f2b(v.z), f2b(v.w) };
    *(us4*)(Wgb + g) = o;
  } else {                                   // Wo: 256*128/4 float4 tasks
    int g = (gid - 12288) * 4;
    float4 v = *(const float4*)(Wo + g);
    us4 o = { f2b(v.x), f2b(v.y), f2b(v.z), f2b(v.w) };
    *(us4*)(Wob + g) = o;
  }
}

// ---------------- kernel 1: QKV projection, 4-way output-slice split ----------------
// (frozen — controlled variable)
__global__ __launch_bounds__(256, 4) void proj_qkv(
    const float* __restrict__ x,
    const u16* __restrict__ Wqkh, const u16* __restrict__ Wqkl,
    const u16* __restrict__ Wgb,
    u16* __restrict__ QbH, u16* __restrict__ QbL,
    u16* __restrict__ KbH, u16* __restrict__ KbL,
    u16* __restrict__ Vb) {
  int tid = threadIdx.x;
  int wave = tid >> 6, lane = tid & 63;
  int l15 = lane & 15, quad = lane >> 4;
  int slice = blockIdx.x >> 8;
  int tb = blockIdx.x & 255;
  int b = tb >> 6;
  int n0 = (tb & 63) * 64;
  int pos = n0 + wave * 16 + l15;
  const float* xb = x + (size_t)b * CHN * NSEQ + pos;
  int nbase = n0 + wave * 16 + quad * 4;

  if (slice < 2) {
    const u16* Wh = Wqkh + slice * 32 * 256;
    const u16* Wl = Wqkl + slice * 32 * 256;
    f32x4 acc[2];
    acc[0] = (f32x4){0.f, 0.f, 0.f, 0.f};
    acc[1] = (f32x4){0.f, 0.f, 0.f, 0.f};
#pragma unroll
    for (int kc = 0; kc < 8; kc++) {
      short8 ahi, alo;
#pragma unroll
      for (int j = 0; j < 8; j++) {
        float xv = xb[(size_t)(kc * 32 + quad * 8 + j) * NSEQ];
        u16 hi = f2b(xv);
        ahi[j] = (short)hi;
        alo[j] = (short)f2b(xv - b2f(hi));
      }
#pragma unroll
      for (int ot = 0; ot < 2; ot++) {
        size_t off = (size_t)(ot * 16 + l15) * 256 + kc * 32 + quad * 8;
        short8 bh = *(const short8*)(Wh + off);
        short8 bl = *(const short8*)(Wl + off);
        acc[ot] = __builtin_amdgcn_mfma_f32_16x16x32_bf16(alo, bh, acc[ot], 0, 0, 0);
        acc[ot] = __builtin_amdgcn_mfma_f32_16x16x32_bf16(ahi, bl, acc[ot], 0, 0, 0);
        acc[ot] = __builtin_amdgcn_mfma_f32_16x16x32_bf16(ahi, bh, acc[ot], 0, 0, 0);
      }
    }
    u16* Hp = (slice == 0) ? QbH : KbH;
    u16* Lp = (slice == 0) ? QbL : KbL;
#pragma unroll
    for (int ot = 0; ot < 2; ot++) {
#pragma unroll
      for (int r = 0; r < 4; r++) {
        float v = acc[ot][r];
        u16 hi = f2b(v);
        u16 lo = f2b(v - b2f(hi));
        size_t nrow = (size_t)(b * NSEQ + nbase + r) * 32 + ot * 16 + l15;
        Hp[nrow] = hi; Lp[nrow] = lo;
      }
    }
  } else {
    const u16* Wg2 = Wgb + (size_t)(slice - 2) * 64 * 256;
    f32x4 acc[4];
#pragma unroll
    for (int oi = 0; oi < 4; oi++) acc[oi] = (f32x4){0.f, 0.f, 0.f, 0.f};
#pragma unroll
    for (int kc = 0; kc < 8; kc++) {
      short8 ahi;
#pragma unroll
      for (int j = 0; j < 8; j++)
        ahi[j] = (short)f2b(xb[(size_t)(kc * 32 + quad * 8 + j) * NSEQ]);
#pragma unroll
      for (int oi = 0; oi < 4; oi++) {
        short8 bg = *(const short8*)(Wg2 + (size_t)(oi * 16 + l15) * 256 + kc * 32 + quad * 8);
        acc[oi] = __builtin_amdgcn_mfma_f32_16x16x32_bf16(ahi, bg, acc[oi], 0, 0, 0);
      }
    }
#pragma unroll
    for (int oi = 0; oi < 4; oi++) {
      int c = (slice - 2) * 64 + oi * 16 + l15;
      us4 pk = { f2b(acc[oi][0]), f2b(acc[oi][1]), f2b(acc[oi][2]), f2b(acc[oi][3]) };
      *(us4*)(Vb + (size_t)(b * 128 + c) * VLD + nbase) = pk;
    }
  }
}

// ---------------- kernel 2: fused flash attention + Wo + epilogue (v6) ----------------
// v5 with __launch_bounds__(512, 1): lifts the 128-VGPR cap that was serializing the
// 12-load prefetch pipeline (VGPR 88 -> ~220 expected; true software pipelining).
// 512 threads: 8 waves = 4 key-splits x 2 row-groups; register-only main loop.
// grid 256 = 4 batches x 64 row-tiles = 1 block/CU, 8 waves/CU (2/SIMD).
__global__ __launch_bounds__(512, 1) void flash_attn(
    const u16* __restrict__ QbH, const u16* __restrict__ QbL,
    const u16* __restrict__ KbH, const u16* __restrict__ KbL,
    const u16* __restrict__ Vb, const u16* __restrict__ Wob,
    const float* __restrict__ x, const float* __restrict__ gammap,
    float* __restrict__ out) {
  // smem map: CombA @0 (32KB, aliased later by BC 20.5KB), CombB @32768 (32KB),
  //           CombLA @65536 (1KB), CombLB @66560 (1KB)
  __shared__ alignas(16) char smem[67584];
  f32x4 (*CombA)[16][64] = (f32x4(*)[16][64])smem;
  f32x4 (*CombB)[16][64] = (f32x4(*)[16][64])(smem + 32768);
  float (*CombLA)[2][64] = (float(*)[2][64])(smem + 65536);
  float (*CombLB)[2][64] = (float(*)[2][64])(smem + 66560);
  u16* BC = (u16*)smem;   // [4 nqt][64 lanes][40]  (80 B lane stride, 16B-aligned)

  int tid = threadIdx.x;
  int wave = tid >> 6, lane = tid & 63;
  int l15 = lane & 15, quad = lane >> 4;
  int sp = wave >> 1, rg = wave & 1;
  int b = blockIdx.x & 3;
  int tile = blockIdx.x >> 2;
  int n0 = tile * 64;
  int nqb = n0 + rg * 32;
  int ms = sp * 1024;                       // this split's key base
  int phase = tile & 31;                    // de-synchronized chunk start
  int rk = ((l15 >> 2) << 3) + (l15 & 3);   // permuted row-in-tile

  short8 qh[2], ql[2];
#pragma unroll
  for (int nt = 0; nt < 2; nt++) {
    size_t qoff = (size_t)(b * NSEQ + nqb + nt * 16 + l15) * 32 + quad * 8;
    qh[nt] = *(const short8*)(QbH + qoff);
    ql[nt] = *(const short8*)(QbL + qoff);
  }
  const u16* KpH = KbH + (size_t)b * NSEQ * 32 + (size_t)(ms + rk) * 32 + quad * 8;
  const u16* KpL = KbL + (size_t)b * NSEQ * 32 + (size_t)(ms + rk) * 32 + quad * 8;
  const u16* Vp  = Vb + (size_t)b * 128 * VLD + (size_t)rk * VLD + ms + quad * 8;

  f32x4 acc[2][8];
#pragma unroll
  for (int nt = 0; nt < 2; nt++)
#pragma unroll
    for (int vt = 0; vt < 8; vt++) acc[nt][vt] = (f32x4){0.f, 0.f, 0.f, 0.f};
  float lsum[2] = {0.f, 0.f};

  // prefetch chunk 'phase'
  short8 kh0 = *(const short8*)(KpH + (size_t)phase * 1024);
  short8 kh1 = *(const short8*)(KpH + (size_t)phase * 1024 + 128);
  short8 kl0 = *(const short8*)(KpL + (size_t)phase * 1024);
  short8 kl1 = *(const short8*)(KpL + (size_t)phase * 1024 + 128);
  short8 vf[8];
#pragma unroll
  for (int vt = 0; vt < 8; vt++)
    vf[vt] = *(const short8*)(Vp + (size_t)((vt >> 1) * 32 + (vt & 1) * 4) * VLD + phase * 32);

  for (int ci = 0; ci < 32; ci++) {
    int cn = (phase + ci + 1) & 31;         // next chunk (wraps harmlessly)
    short8 nkh0 = *(const short8*)(KpH + (size_t)cn * 1024);
    short8 nkh1 = *(const short8*)(KpH + (size_t)cn * 1024 + 128);
    short8 nkl0 = *(const short8*)(KpL + (size_t)cn * 1024);
    short8 nkl1 = *(const short8*)(KpL + (size_t)cn * 1024 + 128);
    short8 nvf[8];
#pragma unroll
    for (int vt = 0; vt < 8; vt++)
      nvf[vt] = *(const short8*)(Vp + (size_t)((vt >> 1) * 32 + (vt & 1) * 4) * VLD + cn * 32);

#pragma unroll
    for (int nt = 0; nt < 2; nt++) {
      // S^T over permuted keys; hi/lo split, small terms first.
      f32x4 z = (f32x4){0.f, 0.f, 0.f, 0.f};
      f32x4 s0 = __builtin_amdgcn_mfma_f32_16x16x32_bf16(kl0, qh[nt], z, 0, 0, 0);
      s0 = __builtin_amdgcn_mfma_f32_16x16x32_bf16(kh0, ql[nt], s0, 0, 0, 0);
      s0 = __builtin_amdgcn_mfma_f32_16x16x32_bf16(kh0, qh[nt], s0, 0, 0, 0);
      f32x4 s1 = __builtin_amdgcn_mfma_f32_16x16x32_bf16(kl1, qh[nt], z, 0, 0, 0);
      s1 = __builtin_amdgcn_mfma_f32_16x16x32_bf16(kh1, ql[nt], s1, 0, 0, 0);
      s1 = __builtin_amdgcn_mfma_f32_16x16x32_bf16(kh1, qh[nt], s1, 0, 0, 0);

      // exp2 -> packed short8 == B-frag of PV (k = quad*8 + j)
      short8 pp;
#pragma unroll
      for (int r = 0; r < 4; r++) {
        float e0 = exp2f(s0[r]);
        float e1 = exp2f(s1[r]);
        lsum[nt] += e0 + e1;
        pp[r] = (short)f2b(e0);
        pp[r + 4] = (short)f2b(e1);
      }
#pragma unroll
      for (int vt = 0; vt < 8; vt++)
        acc[nt][vt] = __builtin_amdgcn_mfma_f32_16x16x32_bf16(vf[vt], pp, acc[nt][vt], 0, 0, 0);
    }

    kh0 = nkh0; kh1 = nkh1; kl0 = nkl0; kl1 = nkl1;
#pragma unroll
    for (int vt = 0; vt < 8; vt++) vf[vt] = nvf[vt];
  }

  // ---- split-K tree combine: (sp2->sp0, sp3->sp1), then sp1->sp0 ----
  if (sp == 2) {
#pragma unroll
    for (int nt = 0; nt < 2; nt++) {
#pragma unroll
      for (int vt = 0; vt < 8; vt++) CombA[rg][nt * 8 + vt][lane] = acc[nt][vt];
      CombLA[rg][nt][lane] = lsum[nt];
    }
  } else if (sp == 3) {
#pragma unroll
    for (int nt = 0; nt < 2; nt++) {
#pragma unroll
      for (int vt = 0; vt < 8; vt++) CombB[rg][nt * 8 + vt][lane] = acc[nt][vt];
      CombLB[rg][nt][lane] = lsum[nt];
    }
  }
  __syncthreads();
  if (sp == 0) {
#pragma unroll
    for (int nt = 0; nt < 2; nt++) {
#pragma unroll
      for (int vt = 0; vt < 8; vt++) acc[nt][vt] += CombA[rg][nt * 8 + vt][lane];
      lsum[nt] += CombLA[rg][nt][lane];
    }
  } else if (sp == 1) {
#pragma unroll
    for (int nt = 0; nt < 2; nt++) {
#pragma unroll
      for (int vt = 0; vt < 8; vt++) acc[nt][vt] += CombB[rg][nt * 8 + vt][lane];
      lsum[nt] += CombLB[rg][nt][lane];
    }
  }
  __syncthreads();
  if (sp == 1) {
#pragma unroll
    for (int nt = 0; nt < 2; nt++) {
#pragma unroll
      for (int vt = 0; vt < 8; vt++) CombA[rg][nt * 8 + vt][lane] = acc[nt][vt];
      CombLA[rg][nt][lane] = lsum[nt];
    }
  }
  __syncthreads();
  if (sp == 0) {
#pragma unroll
    for (int nt = 0; nt < 2; nt++) {
#pragma unroll
      for (int vt = 0; vt < 8; vt++) acc[nt][vt] += CombA[rg][nt * 8 + vt][lane];
      lsum[nt] += CombLA[rg][nt][lane];
    }
    // ---- normalize + pack attn B-frags into BC (aliases CombA; safe post-barrier) ----
#pragma unroll
    for (int nt = 0; nt < 2; nt++) {
      lsum[nt] += __shfl_xor(lsum[nt], 16);
      lsum[nt] += __shfl_xor(lsum[nt], 32);
      float rinv = 1.0f / lsum[nt];          // acc cols all nq = l15: no bcast needed
      int nqt = rg * 2 + nt;
#pragma unroll
      for (int kc = 0; kc < 4; kc++) {
        short8 t;
#pragma unroll
        for (int r = 0; r < 4; r++) {
          t[r]     = (short)f2b(acc[nt][2 * kc][r] * rinv);
          t[r + 4] = (short)f2b(acc[nt][2 * kc + 1][r] * rinv);
        }
        *(short8*)&BC[(size_t)(nqt * 64 + lane) * 40 + kc * 8] = t;
      }
    }
  }
  __syncthreads();

  // ---- Wo GEMM + epilogue across all 8 waves: wave w -> oc-tiles 2w, 2w+1 ----
  short8 bfr[4][4];
#pragma unroll
  for (int nqt = 0; nqt < 4; nqt++)
#pragma unroll
    for (int kc = 0; kc < 4; kc++)
      bfr[nqt][kc] = *(const short8*)&BC[(size_t)(nqt * 64 + lane) * 40 + kc * 8];

  float gamma = *gammap;
#pragma unroll
  for (int mti = 0; mti < 2; mti++) {
    int mt = wave * 2 + mti;
    short8 wf[4];
#pragma unroll
    for (int kc = 0; kc < 4; kc++)
      wf[kc] = *(const short8*)(Wob + (size_t)(mt * 16 + l15) * 128 + kc * 32 + quad * 8);
#pragma unroll
    for (int nqt = 0; nqt < 4; nqt++) {
      f32x4 oacc = (f32x4){0.f, 0.f, 0.f, 0.f};
#pragma unroll
      for (int kc = 0; kc < 4; kc++)
        oacc = __builtin_amdgcn_mfma_f32_16x16x32_bf16(wf[kc], bfr[nqt][kc], oacc, 0, 0, 0);
#pragma unroll
      for (int r = 0; r < 4; r++) {
        int oc = mt * 16 + quad * 4 + r;
        size_t idx = ((size_t)b * CHN + oc) * NSEQ + n0 + nqt * 16 + l15;
        out[idx] = gamma * oacc[r] + x[idx];
      }
    }
  }
}

extern "C" void kernel_launch(void* const* d_in, const int* in_sizes, int n_in,
                              void* d_out, int out_size, void* d_ws, size_t ws_size,
                              hipStream_t stream) {
  const float* x  = (const float*)d_in[0];
  const float* Wt = (const float*)d_in[1];
  const float* Wp = (const float*)d_in[2];
  const float* Wg = (const float*)d_in[3];
  const float* Wo = (const float*)d_in[4];
  const float* gm = (const float*)d_in[5];
  float* out = (float*)d_out;
  u16* ws = (u16*)d_ws;
  u16* QbH  = ws + QH_OFF;
  u16* QbL  = ws + QL_OFF;
  u16* KbH  = ws + KH_OFF;
  u16* KbL  = ws + KL_OFF;
  u16* Vb   = ws + V_OFF;
  u16* Wqkh = ws + WQKH_OFF;
  u16* Wqkl = ws + WQKL_OFF;
  u16* Wgb  = ws + WG_OFF;
  u16* Wob  = ws + WO_OFF;

  prep_weights<<<80, 256, 0, stream>>>(Wt, Wp, Wg, Wo, Wqkh, Wqkl, Wgb, Wob);
  proj_qkv<<<1024, 256, 0, stream>>>(x, Wqkh, Wqkl, Wgb, QbH, QbL, KbH, KbL, Vb);
  flash_attn<<<256, 512, 0, stream>>>(QbH, QbL, KbH, KbL, Vb, Wob, x, gm, out);
}

// Round 9
// 127.986 us; speedup vs baseline: 1.9321x; 1.3601x over previous
//
#include <hip/hip_runtime.h>

#define NSEQ 4096
#define CHN 256

typedef __attribute__((ext_vector_type(8))) short short8;
typedef __attribute__((ext_vector_type(4))) float f32x4;
typedef __attribute__((ext_vector_type(4))) int i32x4;
typedef __attribute__((ext_vector_type(4))) unsigned short us4;
typedef unsigned short u16;

// fp32 -> bf16 round-to-nearest-even (used off the hot path)
__device__ __forceinline__ u16 f2b(float f) {
  unsigned u = __builtin_bit_cast(unsigned, f);
  unsigned r = (u + 0x7fffu + ((u >> 16) & 1u)) >> 16;
  return (u16)r;
}
__device__ __forceinline__ float b2f(u16 h) {
  unsigned u = ((unsigned)h) << 16;
  return __builtin_bit_cast(float, u);
}

// ws layout in u16 elements.
// Kf: [B][128 ci][4 part][64 lane][8]  part: 0=hi/frag0 1=hi/frag1 2=lo/frag0 3=lo/frag1
// Vf: [B][128 ci][8 vt][64 lane][8]
// Wqkf: [2 hl][2 slice][8 kc][2 ot][64][8]   Wgf: [2 half][8 kc][4 oi][64][8]
// Wof: [16 mt][4 kc][64][8]
#define QH_OFF   0u
#define QL_OFF   524288u
#define KF_OFF   1048576u
#define VF_OFF   2097152u
#define WQKF_OFF 4194304u
#define WGF_OFF  4227072u
#define WOF_OFF  4259840u

// ---------------- kernel 0: weight prep -> fragment layouts ----------------
__global__ __launch_bounds__(256) void prep_weights(
    const float* __restrict__ Wt, const float* __restrict__ Wp,
    const float* __restrict__ Wg, const float* __restrict__ Wo,
    u16* __restrict__ Wqkf, u16* __restrict__ Wgf, u16* __restrict__ Wof) {
  int gid = blockIdx.x * 256 + threadIdx.x;  // 80 blocks -> 20480 threads
  if (gid < 4096) {                          // Wt|Wp: 64 rows x 64 float4 tasks
    int row = gid >> 6;
    int c0 = (gid & 63) * 4;
    const float* src;
    float scale = 1.0f;
    if (row < 32) { src = Wt + row * 256; scale = 1.44269504088896340736f; }
    else          { src = Wp + (row - 32) * 256; }
    float4 v = *(const float4*)(src + c0);
    float w0 = v.x * scale, w1 = v.y * scale, w2 = v.z * scale, w3 = v.w * scale;
    us4 hi = { f2b(w0), f2b(w1), f2b(w2), f2b(w3) };
    us4 lo = { f2b(w0 - b2f(hi[0])), f2b(w1 - b2f(hi[1])),
               f2b(w2 - b2f(hi[2])), f2b(w3 - b2f(hi[3])) };
    int slice = row >> 5, ot = (row >> 4) & 1, l15t = row & 15;
    int kc = c0 >> 5, quad_t = (c0 & 31) >> 3, j0 = c0 & 7;
    size_t base = ((size_t)(((slice * 8 + kc) * 2 + ot) * 64 + quad_t * 16 + l15t)) * 8 + j0;
    *(us4*)(Wqkf + base) = hi;
    *(us4*)(Wqkf + base + 16384) = lo;     // hl=1 plane
  } else if (gid < 12288) {                // Wg: 128 rows x 64 float4 tasks
    int t = gid - 4096;
    int row = t >> 6;
    int c0 = (t & 63) * 4;
    float4 v = *(const float4*)(Wg + row * 256 + c0);
    us4 o = { f2b(v.x), f2b(v.y), f2b(v.z), f2b(v.w) };
    int half = row >> 6, oi = (row >> 4) & 3, l15t = row & 15;
    int kc = c0 >> 5, quad_t = (c0 & 31) >> 3, j0 = c0 & 7;
    size_t base = ((size_t)(((half * 8 + kc) * 4 + oi) * 64 + quad_t * 16 + l15t)) * 8 + j0;
    *(us4*)(Wgf + base) = o;
  } else {                                 // Wo: [256][128] -> 8192 float4 tasks
    int t = gid - 12288;
    int g = t * 4;
    int oc = g >> 7, c0 = g & 127;
    float4 v = *(const float4*)(Wo + g);
    us4 o = { f2b(v.x), f2b(v.y), f2b(v.z), f2b(v.w) };
    int mt = oc >> 4, l15t = oc & 15;
    int kc = c0 >> 5, quad_t = (c0 & 31) >> 3, j0 = c0 & 7;
    size_t base = ((size_t)((mt * 4 + kc) * 64 + quad_t * 16 + l15t)) * 8 + j0;
    *(us4*)(Wof + base) = o;
  }
}

// ---------------- kernel 1: QKV projection, fragment-layout outputs ----------------
__global__ __launch_bounds__(256, 4) void proj_qkv(
    const float* __restrict__ x,
    const u16* __restrict__ Wqkf, const u16* __restrict__ Wgf,
    u16* __restrict__ QbH, u16* __restrict__ QbL,
    u16* __restrict__ Kf, u16* __restrict__ Vf) {
  int tid = threadIdx.x;
  int wave = tid >> 6, lane = tid & 63;
  int l15 = lane & 15, quad = lane >> 4;
  int slice = blockIdx.x >> 8;
  int tb = blockIdx.x & 255;
  int b = tb >> 6;
  int n0 = (tb & 63) * 64;
  int pos = n0 + wave * 16 + l15;
  const float* xb = x + (size_t)b * CHN * NSEQ + pos;
  int nbase = n0 + wave * 16 + quad * 4;

  if (slice < 2) {
    f32x4 acc[2];
    acc[0] = (f32x4){0.f, 0.f, 0.f, 0.f};
    acc[1] = (f32x4){0.f, 0.f, 0.f, 0.f};
#pragma unroll
    for (int kc = 0; kc < 8; kc++) {
      short8 ahi, alo;
#pragma unroll
      for (int j = 0; j < 8; j++) {
        float xv = xb[(size_t)(kc * 32 + quad * 8 + j) * NSEQ];
        u16 hi = f2b(xv);
        ahi[j] = (short)hi;
        alo[j] = (short)f2b(xv - b2f(hi));
      }
#pragma unroll
      for (int ot = 0; ot < 2; ot++) {
        size_t off = ((size_t)((slice * 8 + kc) * 2 + ot)) * 512 + lane * 8;
        short8 bh = *(const short8*)(Wqkf + off);
        short8 bl = *(const short8*)(Wqkf + off + 16384);
        acc[ot] = __builtin_amdgcn_mfma_f32_16x16x32_bf16(alo, bh, acc[ot], 0, 0, 0);
        acc[ot] = __builtin_amdgcn_mfma_f32_16x16x32_bf16(ahi, bl, acc[ot], 0, 0, 0);
        acc[ot] = __builtin_amdgcn_mfma_f32_16x16x32_bf16(ahi, bh, acc[ot], 0, 0, 0);
      }
    }
#pragma unroll
    for (int ot = 0; ot < 2; ot++) {
#pragma unroll
      for (int r = 0; r < 4; r++) {
        float v = acc[ot][r];
        u16 hi = f2b(v);
        u16 lo = f2b(v - b2f(hi));
        if (slice == 0) {                        // Q: keep [b][n][32] layout
          size_t nrow = (size_t)(b * NSEQ + nbase + r) * 32 + ot * 16 + l15;
          QbH[nrow] = hi; QbL[nrow] = lo;
        } else {                                 // K: scatter into fragment layout
          int key = nbase + r;
          int oc = ot * 16 + l15;
          int ci = key >> 5, k32 = key & 31;
          int frag = (k32 >> 2) & 1;
          int rkv = k32 - 4 * frag;
          int l15t = ((rkv >> 3) << 2) | (rkv & 3);
          int lane_t = ((oc >> 3) << 4) + l15t;
          size_t base = (size_t)b * 262144 + (size_t)(ci * 4 + frag) * 512 + lane_t * 8 + (oc & 7);
          Kf[base] = hi;
          Kf[base + 1024] = lo;                  // parts 2/3 = +2*512
        }
      }
    }
  } else {
    f32x4 acc[4];
#pragma unroll
    for (int oi = 0; oi < 4; oi++) acc[oi] = (f32x4){0.f, 0.f, 0.f, 0.f};
#pragma unroll
    for (int kc = 0; kc < 8; kc++) {
      short8 ahi;
#pragma unroll
      for (int j = 0; j < 8; j++)
        ahi[j] = (short)f2b(xb[(size_t)(kc * 32 + quad * 8 + j) * NSEQ]);
#pragma unroll
      for (int oi = 0; oi < 4; oi++) {
        short8 bg = *(const short8*)(Wgf + ((size_t)(((slice - 2) * 8 + kc) * 4 + oi)) * 512 + lane * 8);
        acc[oi] = __builtin_amdgcn_mfma_f32_16x16x32_bf16(ahi, bg, acc[oi], 0, 0, 0);
      }
    }
#pragma unroll
    for (int oi = 0; oi < 4; oi++) {
      int ch = (slice - 2) * 64 + oi * 16 + l15;
      int vt = ((ch >> 5) << 1) | ((ch >> 2) & 1);
      int rkv = (ch & 31) - ((ch >> 2) & 1) * 4;
      int l15t = ((rkv >> 3) << 2) | (rkv & 3);
      int ci = nbase >> 5, mc = nbase & 31;
      int lane_t = ((mc >> 3) << 4) + l15t;
      us4 pk = { f2b(acc[oi][0]), f2b(acc[oi][1]), f2b(acc[oi][2]), f2b(acc[oi][3]) };
      size_t addr = (size_t)b * 524288 + (size_t)(ci * 8 + vt) * 512 + lane_t * 8 + (mc & 7);
      *(us4*)(Vf + addr) = pk;
    }
  }
}

// ---------------- kernel 2: fused flash attention + Wo + epilogue (v7) ----------------
// All main-loop loads are lane-contiguous 1 KB (fragment-layout Kf/Vf) -> coalescable.
// Truncation-pack P (softmax ratio cancels bias). Structure otherwise = v6:
// 8 waves = 4 sp x 2 rg, 32 Q rows/wave, split-K-4 combined in LDS; grid 256.
__global__ __launch_bounds__(512, 1) void flash_attn(
    const u16* __restrict__ QbH, const u16* __restrict__ QbL,
    const u16* __restrict__ Kf, const u16* __restrict__ Vf,
    const u16* __restrict__ Wof,
    const float* __restrict__ x, const float* __restrict__ gammap,
    float* __restrict__ out) {
  __shared__ alignas(16) char smem[67584];
  f32x4 (*CombA)[16][64] = (f32x4(*)[16][64])smem;
  f32x4 (*CombB)[16][64] = (f32x4(*)[16][64])(smem + 32768);
  float (*CombLA)[2][64] = (float(*)[2][64])(smem + 65536);
  float (*CombLB)[2][64] = (float(*)[2][64])(smem + 66560);
  u16* BC = (u16*)smem;   // [4 nqt][64 lanes][40] aliases CombA post-barrier

  int tid = threadIdx.x;
  int wave = tid >> 6, lane = tid & 63;
  int l15 = lane & 15, quad = lane >> 4;
  int sp = wave >> 1, rg = wave & 1;
  int b = blockIdx.x & 3;
  int tile = blockIdx.x >> 2;
  int n0 = tile * 64;
  int nqb = n0 + rg * 32;
  int phase = tile & 31;

  short8 qh[2], ql[2];
#pragma unroll
  for (int nt = 0; nt < 2; nt++) {
    size_t qoff = (size_t)(b * NSEQ + nqb + nt * 16 + l15) * 32 + quad * 8;
    qh[nt] = *(const short8*)(QbH + qoff);
    ql[nt] = *(const short8*)(QbL + qoff);
  }
  const u16* Kfb = Kf + (size_t)b * 262144 + lane * 8;
  const u16* Vfb = Vf + (size_t)b * 524288 + lane * 8;

  f32x4 acc[2][8];
#pragma unroll
  for (int nt = 0; nt < 2; nt++)
#pragma unroll
    for (int vt = 0; vt < 8; vt++) acc[nt][vt] = (f32x4){0.f, 0.f, 0.f, 0.f};
  float lsum[2] = {0.f, 0.f};

  // prefetch chunk 'phase' of this split (global chunk ck = sp*32 + phase)
  int ck0 = sp * 32 + phase;
  short8 kh0 = *(const short8*)(Kfb + (size_t)(ck0 * 4 + 0) * 512);
  short8 kh1 = *(const short8*)(Kfb + (size_t)(ck0 * 4 + 1) * 512);
  short8 kl0 = *(const short8*)(Kfb + (size_t)(ck0 * 4 + 2) * 512);
  short8 kl1 = *(const short8*)(Kfb + (size_t)(ck0 * 4 + 3) * 512);
  short8 vf[8];
#pragma unroll
  for (int vt = 0; vt < 8; vt++)
    vf[vt] = *(const short8*)(Vfb + (size_t)(ck0 * 8 + vt) * 512);

  for (int ci = 0; ci < 32; ci++) {
    int ck = sp * 32 + ((phase + ci + 1) & 31);   // next chunk (wraps harmlessly)
    short8 nkh0 = *(const short8*)(Kfb + (size_t)(ck * 4 + 0) * 512);
    short8 nkh1 = *(const short8*)(Kfb + (size_t)(ck * 4 + 1) * 512);
    short8 nkl0 = *(const short8*)(Kfb + (size_t)(ck * 4 + 2) * 512);
    short8 nkl1 = *(const short8*)(Kfb + (size_t)(ck * 4 + 3) * 512);
    short8 nvf[8];
#pragma unroll
    for (int vt = 0; vt < 8; vt++)
      nvf[vt] = *(const short8*)(Vfb + (size_t)(ck * 8 + vt) * 512);

#pragma unroll
    for (int nt = 0; nt < 2; nt++) {
      f32x4 z = (f32x4){0.f, 0.f, 0.f, 0.f};
      f32x4 s0 = __builtin_amdgcn_mfma_f32_16x16x32_bf16(kl0, qh[nt], z, 0, 0, 0);
      s0 = __builtin_amdgcn_mfma_f32_16x16x32_bf16(kh0, ql[nt], s0, 0, 0, 0);
      s0 = __builtin_amdgcn_mfma_f32_16x16x32_bf16(kh0, qh[nt], s0, 0, 0, 0);
      f32x4 s1 = __builtin_amdgcn_mfma_f32_16x16x32_bf16(kl1, qh[nt], z, 0, 0, 0);
      s1 = __builtin_amdgcn_mfma_f32_16x16x32_bf16(kh1, ql[nt], s1, 0, 0, 0);
      s1 = __builtin_amdgcn_mfma_f32_16x16x32_bf16(kh1, qh[nt], s1, 0, 0, 0);

      // exp2 + truncation-pack -> pp == B-frag of PV
      float e0 = exp2f(s0[0]), e1 = exp2f(s0[1]), e2 = exp2f(s0[2]), e3 = exp2f(s0[3]);
      float e4 = exp2f(s1[0]), e5 = exp2f(s1[1]), e6 = exp2f(s1[2]), e7 = exp2f(s1[3]);
      lsum[nt] += ((e0 + e1) + (e2 + e3)) + ((e4 + e5) + (e6 + e7));
      i32x4 pi;
      pi[0] = (int)((__builtin_bit_cast(unsigned, e0) >> 16) | (__builtin_bit_cast(unsigned, e1) & 0xffff0000u));
      pi[1] = (int)((__builtin_bit_cast(unsigned, e2) >> 16) | (__builtin_bit_cast(unsigned, e3) & 0xffff0000u));
      pi[2] = (int)((__builtin_bit_cast(unsigned, e4) >> 16) | (__builtin_bit_cast(unsigned, e5) & 0xffff0000u));
      pi[3] = (int)((__builtin_bit_cast(unsigned, e6) >> 16) | (__builtin_bit_cast(unsigned, e7) & 0xffff0000u));
      short8 pp = __builtin_bit_cast(short8, pi);
#pragma unroll
      for (int vt = 0; vt < 8; vt++)
        acc[nt][vt] = __builtin_amdgcn_mfma_f32_16x16x32_bf16(vf[vt], pp, acc[nt][vt], 0, 0, 0);
    }

    kh0 = nkh0; kh1 = nkh1; kl0 = nkl0; kl1 = nkl1;
#pragma unroll
    for (int vt = 0; vt < 8; vt++) vf[vt] = nvf[vt];
  }

  // ---- split-K tree combine: (sp2->sp0, sp3->sp1), then sp1->sp0 ----
  if (sp == 2) {
#pragma unroll
    for (int nt = 0; nt < 2; nt++) {
#pragma unroll
      for (int vt = 0; vt < 8; vt++) CombA[rg][nt * 8 + vt][lane] = acc[nt][vt];
      CombLA[rg][nt][lane] = lsum[nt];
    }
  } else if (sp == 3) {
#pragma unroll
    for (int nt = 0; nt < 2; nt++) {
#pragma unroll
      for (int vt = 0; vt < 8; vt++) CombB[rg][nt * 8 + vt][lane] = acc[nt][vt];
      CombLB[rg][nt][lane] = lsum[nt];
    }
  }
  __syncthreads();
  if (sp == 0) {
#pragma unroll
    for (int nt = 0; nt < 2; nt++) {
#pragma unroll
      for (int vt = 0; vt < 8; vt++) acc[nt][vt] += CombA[rg][nt * 8 + vt][lane];
      lsum[nt] += CombLA[rg][nt][lane];
    }
  } else if (sp == 1) {
#pragma unroll
    for (int nt = 0; nt < 2; nt++) {
#pragma unroll
      for (int vt = 0; vt < 8; vt++) acc[nt][vt] += CombB[rg][nt * 8 + vt][lane];
      lsum[nt] += CombLB[rg][nt][lane];
    }
  }
  __syncthreads();
  if (sp == 1) {
#pragma unroll
    for (int nt = 0; nt < 2; nt++) {
#pragma unroll
      for (int vt = 0; vt < 8; vt++) CombA[rg][nt * 8 + vt][lane] = acc[nt][vt];
      CombLA[rg][nt][lane] = lsum[nt];
    }
  }
  __syncthreads();
  if (sp == 0) {
#pragma unroll
    for (int nt = 0; nt < 2; nt++) {
#pragma unroll
      for (int vt = 0; vt < 8; vt++) acc[nt][vt] += CombA[rg][nt * 8 + vt][lane];
      lsum[nt] += CombLA[rg][nt][lane];
    }
#pragma unroll
    for (int nt = 0; nt < 2; nt++) {
      lsum[nt] += __shfl_xor(lsum[nt], 16);
      lsum[nt] += __shfl_xor(lsum[nt], 32);
      float rinv = 1.0f / lsum[nt];
      int nqt = rg * 2 + nt;
#pragma unroll
      for (int kc = 0; kc < 4; kc++) {
        short8 t;
#pragma unroll
        for (int r = 0; r < 4; r++) {
          t[r]     = (short)f2b(acc[nt][2 * kc][r] * rinv);
          t[r + 4] = (short)f2b(acc[nt][2 * kc + 1][r] * rinv);
        }
        *(short8*)&BC[(size_t)(nqt * 64 + lane) * 40 + kc * 8] = t;
      }
    }
  }
  __syncthreads();

  // ---- Wo GEMM + epilogue: wave w -> oc-tiles 2w, 2w+1 ----
  short8 bfr[4][4];
#pragma unroll
  for (int nqt = 0; nqt < 4; nqt++)
#pragma unroll
    for (int kc = 0; kc < 4; kc++)
      bfr[nqt][kc] = *(const short8*)&BC[(size_t)(nqt * 64 + lane) * 40 + kc * 8];

  float gamma = *gammap;
#pragma unroll
  for (int mti = 0; mti < 2; mti++) {
    int mt = wave * 2 + mti;
    short8 wf[4];
#pragma unroll
    for (int kc = 0; kc < 4; kc++)
      wf[kc] = *(const short8*)(Wof + (size_t)(mt * 4 + kc) * 512 + lane * 8);
#pragma unroll
    for (int nqt = 0; nqt < 4; nqt++) {
      f32x4 oacc = (f32x4){0.f, 0.f, 0.f, 0.f};
#pragma unroll
      for (int kc = 0; kc < 4; kc++)
        oacc = __builtin_amdgcn_mfma_f32_16x16x32_bf16(wf[kc], bfr[nqt][kc], oacc, 0, 0, 0);
#pragma unroll
      for (int r = 0; r < 4; r++) {
        int oc = mt * 16 + quad * 4 + r;
        size_t idx = ((size_t)b * CHN + oc) * NSEQ + n0 + nqt * 16 + l15;
        out[idx] = gamma * oacc[r] + x[idx];
      }
    }
  }
}

extern "C" void kernel_launch(void* const* d_in, const int* in_sizes, int n_in,
                              void* d_out, int out_size, void* d_ws, size_t ws_size,
                              hipStream_t stream) {
  const float* x  = (const float*)d_in[0];
  const float* Wt = (const float*)d_in[1];
  const float* Wp = (const float*)d_in[2];
  const float* Wg = (const float*)d_in[3];
  const float* Wo = (const float*)d_in[4];
  const float* gm = (const float*)d_in[5];
  float* out = (float*)d_out;
  u16* ws = (u16*)d_ws;
  u16* QbH  = ws + QH_OFF;
  u16* QbL  = ws + QL_OFF;
  u16* Kf   = ws + KF_OFF;
  u16* Vf   = ws + VF_OFF;
  u16* Wqkf = ws + WQKF_OFF;
  u16* Wgf  = ws + WGF_OFF;
  u16* Wof  = ws + WOF_OFF;

  prep_weights<<<80, 256, 0, stream>>>(Wt, Wp, Wg, Wo, Wqkf, Wgf, Wof);
  proj_qkv<<<1024, 256, 0, stream>>>(x, Wqkf, Wgf, QbH, QbL, Kf, Vf);
  flash_attn<<<256, 512, 0, stream>>>(QbH, QbL, Kf, Vf, Wof, x, gm, out);
}

// Round 10
// 119.845 us; speedup vs baseline: 2.0634x; 1.0679x over previous
//
#include <hip/hip_runtime.h>

#define NSEQ 4096
#define CHN 256

typedef __attribute__((ext_vector_type(8))) short short8;
typedef __attribute__((ext_vector_type(4))) float f32x4;
typedef __attribute__((ext_vector_type(4))) int i32x4;
typedef __attribute__((ext_vector_type(4))) unsigned short us4;
typedef unsigned short u16;

// fp32 -> bf16 round-to-nearest-even (off the hot path)
__device__ __forceinline__ u16 f2b(float f) {
  unsigned u = __builtin_bit_cast(unsigned, f);
  unsigned r = (u + 0x7fffu + ((u >> 16) & 1u)) >> 16;
  return (u16)r;
}
__device__ __forceinline__ float b2f(u16 h) {
  unsigned u = ((unsigned)h) << 16;
  return __builtin_bit_cast(float, u);
}

// raw v_exp_f32 (2^x); ocml exp2f carries ~8 guard instrs we don't need (|x|<64)
#if __has_builtin(__builtin_amdgcn_exp2f)
#define FEXP2(x) __builtin_amdgcn_exp2f(x)
#else
__device__ __forceinline__ float fexp2_asm(float x) {
  float r;
  asm("v_exp_f32 %0, %1\n\ts_nop 0" : "=v"(r) : "v"(x));  // s_nop covers trans->VALU hazard
  return r;
}
#define FEXP2(x) fexp2_asm(x)
#endif

// ws layout in u16 elements.
// Kf: [B][128 ci][4 part][64 lane][8]  part: 0=hi/frag0 1=hi/frag1 2=lo/frag0 3=lo/frag1
// Vf: [B][128 ci][8 vt][64 lane][8]
// Wqkf: [2 hl][2 slice][8 kc][2 ot][64][8]   Wgf: [2 half][8 kc][4 oi][64][8]
// Wof: [16 mt][4 kc][64][8]
#define QH_OFF   0u
#define QL_OFF   524288u
#define KF_OFF   1048576u
#define VF_OFF   2097152u
#define WQKF_OFF 4194304u
#define WGF_OFF  4227072u
#define WOF_OFF  4259840u

// ---------------- kernel 0: weight prep -> fragment layouts (frozen from r9) ----------------
__global__ __launch_bounds__(256) void prep_weights(
    const float* __restrict__ Wt, const float* __restrict__ Wp,
    const float* __restrict__ Wg, const float* __restrict__ Wo,
    u16* __restrict__ Wqkf, u16* __restrict__ Wgf, u16* __restrict__ Wof) {
  int gid = blockIdx.x * 256 + threadIdx.x;
  if (gid < 4096) {
    int row = gid >> 6;
    int c0 = (gid & 63) * 4;
    const float* src;
    float scale = 1.0f;
    if (row < 32) { src = Wt + row * 256; scale = 1.44269504088896340736f; }
    else          { src = Wp + (row - 32) * 256; }
    float4 v = *(const float4*)(src + c0);
    float w0 = v.x * scale, w1 = v.y * scale, w2 = v.z * scale, w3 = v.w * scale;
    us4 hi = { f2b(w0), f2b(w1), f2b(w2), f2b(w3) };
    us4 lo = { f2b(w0 - b2f(hi[0])), f2b(w1 - b2f(hi[1])),
               f2b(w2 - b2f(hi[2])), f2b(w3 - b2f(hi[3])) };
    int slice = row >> 5, ot = (row >> 4) & 1, l15t = row & 15;
    int kc = c0 >> 5, quad_t = (c0 & 31) >> 3, j0 = c0 & 7;
    size_t base = ((size_t)(((slice * 8 + kc) * 2 + ot) * 64 + quad_t * 16 + l15t)) * 8 + j0;
    *(us4*)(Wqkf + base) = hi;
    *(us4*)(Wqkf + base + 16384) = lo;
  } else if (gid < 12288) {
    int t = gid - 4096;
    int row = t >> 6;
    int c0 = (t & 63) * 4;
    float4 v = *(const float4*)(Wg + row * 256 + c0);
    us4 o = { f2b(v.x), f2b(v.y), f2b(v.z), f2b(v.w) };
    int half = row >> 6, oi = (row >> 4) & 3, l15t = row & 15;
    int kc = c0 >> 5, quad_t = (c0 & 31) >> 3, j0 = c0 & 7;
    size_t base = ((size_t)(((half * 8 + kc) * 4 + oi) * 64 + quad_t * 16 + l15t)) * 8 + j0;
    *(us4*)(Wgf + base) = o;
  } else {
    int t = gid - 12288;
    int g = t * 4;
    int oc = g >> 7, c0 = g & 127;
    float4 v = *(const float4*)(Wo + g);
    us4 o = { f2b(v.x), f2b(v.y), f2b(v.z), f2b(v.w) };
    int mt = oc >> 4, l15t = oc & 15;
    int kc = c0 >> 5, quad_t = (c0 & 31) >> 3, j0 = c0 & 7;
    size_t base = ((size_t)((mt * 4 + kc) * 64 + quad_t * 16 + l15t)) * 8 + j0;
    *(us4*)(Wof + base) = o;
  }
}

// ---------------- kernel 1: QKV projection (frozen from r9) ----------------
__global__ __launch_bounds__(256, 4) void proj_qkv(
    const float* __restrict__ x,
    const u16* __restrict__ Wqkf, const u16* __restrict__ Wgf,
    u16* __restrict__ QbH, u16* __restrict__ QbL,
    u16* __restrict__ Kf, u16* __restrict__ Vf) {
  int tid = threadIdx.x;
  int wave = tid >> 6, lane = tid & 63;
  int l15 = lane & 15, quad = lane >> 4;
  int slice = blockIdx.x >> 8;
  int tb = blockIdx.x & 255;
  int b = tb >> 6;
  int n0 = (tb & 63) * 64;
  int pos = n0 + wave * 16 + l15;
  const float* xb = x + (size_t)b * CHN * NSEQ + pos;
  int nbase = n0 + wave * 16 + quad * 4;

  if (slice < 2) {
    f32x4 acc[2];
    acc[0] = (f32x4){0.f, 0.f, 0.f, 0.f};
    acc[1] = (f32x4){0.f, 0.f, 0.f, 0.f};
#pragma unroll
    for (int kc = 0; kc < 8; kc++) {
      short8 ahi, alo;
#pragma unroll
      for (int j = 0; j < 8; j++) {
        float xv = xb[(size_t)(kc * 32 + quad * 8 + j) * NSEQ];
        u16 hi = f2b(xv);
        ahi[j] = (short)hi;
        alo[j] = (short)f2b(xv - b2f(hi));
      }
#pragma unroll
      for (int ot = 0; ot < 2; ot++) {
        size_t off = ((size_t)((slice * 8 + kc) * 2 + ot)) * 512 + lane * 8;
        short8 bh = *(const short8*)(Wqkf + off);
        short8 bl = *(const short8*)(Wqkf + off + 16384);
        acc[ot] = __builtin_amdgcn_mfma_f32_16x16x32_bf16(alo, bh, acc[ot], 0, 0, 0);
        acc[ot] = __builtin_amdgcn_mfma_f32_16x16x32_bf16(ahi, bl, acc[ot], 0, 0, 0);
        acc[ot] = __builtin_amdgcn_mfma_f32_16x16x32_bf16(ahi, bh, acc[ot], 0, 0, 0);
      }
    }
#pragma unroll
    for (int ot = 0; ot < 2; ot++) {
#pragma unroll
      for (int r = 0; r < 4; r++) {
        float v = acc[ot][r];
        u16 hi = f2b(v);
        u16 lo = f2b(v - b2f(hi));
        if (slice == 0) {
          size_t nrow = (size_t)(b * NSEQ + nbase + r) * 32 + ot * 16 + l15;
          QbH[nrow] = hi; QbL[nrow] = lo;
        } else {
          int key = nbase + r;
          int oc = ot * 16 + l15;
          int ci = key >> 5, k32 = key & 31;
          int frag = (k32 >> 2) & 1;
          int rkv = k32 - 4 * frag;
          int l15t = ((rkv >> 3) << 2) | (rkv & 3);
          int lane_t = ((oc >> 3) << 4) + l15t;
          size_t base = (size_t)b * 262144 + (size_t)(ci * 4 + frag) * 512 + lane_t * 8 + (oc & 7);
          Kf[base] = hi;
          Kf[base + 1024] = lo;
        }
      }
    }
  } else {
    f32x4 acc[4];
#pragma unroll
    for (int oi = 0; oi < 4; oi++) acc[oi] = (f32x4){0.f, 0.f, 0.f, 0.f};
#pragma unroll
    for (int kc = 0; kc < 8; kc++) {
      short8 ahi;
#pragma unroll
      for (int j = 0; j < 8; j++)
        ahi[j] = (short)f2b(xb[(size_t)(kc * 32 + quad * 8 + j) * NSEQ]);
#pragma unroll
      for (int oi = 0; oi < 4; oi++) {
        short8 bg = *(const short8*)(Wgf + ((size_t)(((slice - 2) * 8 + kc) * 4 + oi)) * 512 + lane * 8);
        acc[oi] = __builtin_amdgcn_mfma_f32_16x16x32_bf16(ahi, bg, acc[oi], 0, 0, 0);
      }
    }
#pragma unroll
    for (int oi = 0; oi < 4; oi++) {
      int ch = (slice - 2) * 64 + oi * 16 + l15;
      int vt = ((ch >> 5) << 1) | ((ch >> 2) & 1);
      int rkv = (ch & 31) - ((ch >> 2) & 1) * 4;
      int l15t = ((rkv >> 3) << 2) | (rkv & 3);
      int ci = nbase >> 5, mc = nbase & 31;
      int lane_t = ((mc >> 3) << 4) + l15t;
      us4 pk = { f2b(acc[oi][0]), f2b(acc[oi][1]), f2b(acc[oi][2]), f2b(acc[oi][3]) };
      size_t addr = (size_t)b * 524288 + (size_t)(ci * 8 + vt) * 512 + lane_t * 8 + (mc & 7);
      *(us4*)(Vf + addr) = pk;
    }
  }
}

// ---------------- kernel 2: fused flash attention + Wo + epilogue (v8) ----------------
// v7 + VALU diet: raw v_exp_f32, manual 2x unroll with A/B register sets (no copy movs),
// pointer-increment addressing (no wrap/phase). Structure otherwise identical.
__global__ __launch_bounds__(512, 1) void flash_attn(
    const u16* __restrict__ QbH, const u16* __restrict__ QbL,
    const u16* __restrict__ Kf, const u16* __restrict__ Vf,
    const u16* __restrict__ Wof,
    const float* __restrict__ x, const float* __restrict__ gammap,
    float* __restrict__ out) {
  __shared__ alignas(16) char smem[67584];
  f32x4 (*CombA)[16][64] = (f32x4(*)[16][64])smem;
  f32x4 (*CombB)[16][64] = (f32x4(*)[16][64])(smem + 32768);
  float (*CombLA)[2][64] = (float(*)[2][64])(smem + 65536);
  float (*CombLB)[2][64] = (float(*)[2][64])(smem + 66560);
  u16* BC = (u16*)smem;   // [4 nqt][64 lanes][40] aliases CombA post-barrier

  int tid = threadIdx.x;
  int wave = tid >> 6, lane = tid & 63;
  int l15 = lane & 15, quad = lane >> 4;
  int sp = wave >> 1, rg = wave & 1;
  int b = blockIdx.x & 3;
  int tile = blockIdx.x >> 2;
  int n0 = tile * 64;
  int nqb = n0 + rg * 32;

  short8 qh[2], ql[2];
#pragma unroll
  for (int nt = 0; nt < 2; nt++) {
    size_t qoff = (size_t)(b * NSEQ + nqb + nt * 16 + l15) * 32 + quad * 8;
    qh[nt] = *(const short8*)(QbH + qoff);
    ql[nt] = *(const short8*)(QbL + qoff);
  }
  const u16* Kp = Kf + (size_t)b * 262144 + (size_t)sp * 32 * 2048 + lane * 8;
  const u16* Vp = Vf + (size_t)b * 524288 + (size_t)sp * 32 * 4096 + lane * 8;

  f32x4 acc[2][8];
#pragma unroll
  for (int nt = 0; nt < 2; nt++)
#pragma unroll
    for (int vt = 0; vt < 8; vt++) acc[nt][vt] = (f32x4){0.f, 0.f, 0.f, 0.f};
  float lsum[2] = {0.f, 0.f};

  short8 kA[4], vA[8], kB[4], vB[8];
#pragma unroll
  for (int p = 0; p < 4; p++) kA[p] = *(const short8*)(Kp + p * 512);
#pragma unroll
  for (int vt = 0; vt < 8; vt++) vA[vt] = *(const short8*)(Vp + vt * 512);

  // one chunk: QK^T (hi/lo, small terms first) -> exp2 -> truncation-pack -> PV
  auto compute = [&](const short8* k, const short8* v) {
#pragma unroll
    for (int nt = 0; nt < 2; nt++) {
      f32x4 z = (f32x4){0.f, 0.f, 0.f, 0.f};
      f32x4 s0 = __builtin_amdgcn_mfma_f32_16x16x32_bf16(k[2], qh[nt], z, 0, 0, 0);
      s0 = __builtin_amdgcn_mfma_f32_16x16x32_bf16(k[0], ql[nt], s0, 0, 0, 0);
      s0 = __builtin_amdgcn_mfma_f32_16x16x32_bf16(k[0], qh[nt], s0, 0, 0, 0);
      f32x4 s1 = __builtin_amdgcn_mfma_f32_16x16x32_bf16(k[3], qh[nt], z, 0, 0, 0);
      s1 = __builtin_amdgcn_mfma_f32_16x16x32_bf16(k[1], ql[nt], s1, 0, 0, 0);
      s1 = __builtin_amdgcn_mfma_f32_16x16x32_bf16(k[1], qh[nt], s1, 0, 0, 0);

      float e0 = FEXP2(s0[0]), e1 = FEXP2(s0[1]), e2 = FEXP2(s0[2]), e3 = FEXP2(s0[3]);
      float e4 = FEXP2(s1[0]), e5 = FEXP2(s1[1]), e6 = FEXP2(s1[2]), e7 = FEXP2(s1[3]);
      lsum[nt] += ((e0 + e1) + (e2 + e3)) + ((e4 + e5) + (e6 + e7));
      i32x4 pi;
      pi[0] = (int)((__builtin_bit_cast(unsigned, e0) >> 16) | (__builtin_bit_cast(unsigned, e1) & 0xffff0000u));
      pi[1] = (int)((__builtin_bit_cast(unsigned, e2) >> 16) | (__builtin_bit_cast(unsigned, e3) & 0xffff0000u));
      pi[2] = (int)((__builtin_bit_cast(unsigned, e4) >> 16) | (__builtin_bit_cast(unsigned, e5) & 0xffff0000u));
      pi[3] = (int)((__builtin_bit_cast(unsigned, e6) >> 16) | (__builtin_bit_cast(unsigned, e7) & 0xffff0000u));
      short8 pp = __builtin_bit_cast(short8, pi);
#pragma unroll
      for (int vt = 0; vt < 8; vt++)
        acc[nt][vt] = __builtin_amdgcn_mfma_f32_16x16x32_bf16(v[vt], pp, acc[nt][vt], 0, 0, 0);
    }
  };

  for (int ci = 0; ci < 16; ci++) {
    Kp += 2048; Vp += 4096;
#pragma unroll
    for (int p = 0; p < 4; p++) kB[p] = *(const short8*)(Kp + p * 512);
#pragma unroll
    for (int vt = 0; vt < 8; vt++) vB[vt] = *(const short8*)(Vp + vt * 512);
    compute(kA, vA);

    Kp += 2048; Vp += 4096;
#pragma unroll
    for (int p = 0; p < 4; p++) kA[p] = *(const short8*)(Kp + p * 512);
#pragma unroll
    for (int vt = 0; vt < 8; vt++) vA[vt] = *(const short8*)(Vp + vt * 512);
    compute(kB, vB);
  }
  // final prefetch (chunk sp*32+32) reads one-past-range into adjacent ws regions: harmless.

  // ---- split-K tree combine: (sp2->sp0, sp3->sp1), then sp1->sp0 ----
  if (sp == 2) {
#pragma unroll
    for (int nt = 0; nt < 2; nt++) {
#pragma unroll
      for (int vt = 0; vt < 8; vt++) CombA[rg][nt * 8 + vt][lane] = acc[nt][vt];
      CombLA[rg][nt][lane] = lsum[nt];
    }
  } else if (sp == 3) {
#pragma unroll
    for (int nt = 0; nt < 2; nt++) {
#pragma unroll
      for (int vt = 0; vt < 8; vt++) CombB[rg][nt * 8 + vt][lane] = acc[nt][vt];
      CombLB[rg][nt][lane] = lsum[nt];
    }
  }
  __syncthreads();
  if (sp == 0) {
#pragma unroll
    for (int nt = 0; nt < 2; nt++) {
#pragma unroll
      for (int vt = 0; vt < 8; vt++) acc[nt][vt] += CombA[rg][nt * 8 + vt][lane];
      lsum[nt] += CombLA[rg][nt][lane];
    }
  } else if (sp == 1) {
#pragma unroll
    for (int nt = 0; nt < 2; nt++) {
#pragma unroll
      for (int vt = 0; vt < 8; vt++) acc[nt][vt] += CombB[rg][nt * 8 + vt][lane];
      lsum[nt] += CombLB[rg][nt][lane];
    }
  }
  __syncthreads();
  if (sp == 1) {
#pragma unroll
    for (int nt = 0; nt < 2; nt++) {
#pragma unroll
      for (int vt = 0; vt < 8; vt++) CombA[rg][nt * 8 + vt][lane] = acc[nt][vt];
      CombLA[rg][nt][lane] = lsum[nt];
    }
  }
  __syncthreads();
  if (sp == 0) {
#pragma unroll
    for (int nt = 0; nt < 2; nt++) {
#pragma unroll
      for (int vt = 0; vt < 8; vt++) acc[nt][vt] += CombA[rg][nt * 8 + vt][lane];
      lsum[nt] += CombLA[rg][nt][lane];
    }
#pragma unroll
    for (int nt = 0; nt < 2; nt++) {
      lsum[nt] += __shfl_xor(lsum[nt], 16);
      lsum[nt] += __shfl_xor(lsum[nt], 32);
      float rinv = 1.0f / lsum[nt];
      int nqt = rg * 2 + nt;
#pragma unroll
      for (int kc = 0; kc < 4; kc++) {
        short8 t;
#pragma unroll
        for (int r = 0; r < 4; r++) {
          t[r]     = (short)f2b(acc[nt][2 * kc][r] * rinv);
          t[r + 4] = (short)f2b(acc[nt][2 * kc + 1][r] * rinv);
        }
        *(short8*)&BC[(size_t)(nqt * 64 + lane) * 40 + kc * 8] = t;
      }
    }
  }
  __syncthreads();

  // ---- Wo GEMM + epilogue: wave w -> oc-tiles 2w, 2w+1 ----
  short8 bfr[4][4];
#pragma unroll
  for (int nqt = 0; nqt < 4; nqt++)
#pragma unroll
    for (int kc = 0; kc < 4; kc++)
      bfr[nqt][kc] = *(const short8*)&BC[(size_t)(nqt * 64 + lane) * 40 + kc * 8];

  float gamma = *gammap;
#pragma unroll
  for (int mti = 0; mti < 2; mti++) {
    int mt = wave * 2 + mti;
    short8 wf[4];
#pragma unroll
    for (int kc = 0; kc < 4; kc++)
      wf[kc] = *(const short8*)(Wof + (size_t)(mt * 4 + kc) * 512 + lane * 8);
#pragma unroll
    for (int nqt = 0; nqt < 4; nqt++) {
      f32x4 oacc = (f32x4){0.f, 0.f, 0.f, 0.f};
#pragma unroll
      for (int kc = 0; kc < 4; kc++)
        oacc = __builtin_amdgcn_mfma_f32_16x16x32_bf16(wf[kc], bfr[nqt][kc], oacc, 0, 0, 0);
#pragma unroll
      for (int r = 0; r < 4; r++) {
        int oc = mt * 16 + quad * 4 + r;
        size_t idx = ((size_t)b * CHN + oc) * NSEQ + n0 + nqt * 16 + l15;
        out[idx] = gamma * oacc[r] + x[idx];
      }
    }
  }
}

extern "C" void kernel_launch(void* const* d_in, const int* in_sizes, int n_in,
                              void* d_out, int out_size, void* d_ws, size_t ws_size,
                              hipStream_t stream) {
  const float* x  = (const float*)d_in[0];
  const float* Wt = (const float*)d_in[1];
  const float* Wp = (const float*)d_in[2];
  const float* Wg = (const float*)d_in[3];
  const float* Wo = (const float*)d_in[4];
  const float* gm = (const float*)d_in[5];
  float* out = (float*)d_out;
  u16* ws = (u16*)d_ws;
  u16* QbH  = ws + QH_OFF;
  u16* QbL  = ws + QL_OFF;
  u16* Kf   = ws + KF_OFF;
  u16* Vf   = ws + VF_OFF;
  u16* Wqkf = ws + WQKF_OFF;
  u16* Wgf  = ws + WGF_OFF;
  u16* Wof  = ws + WOF_OFF;

  prep_weights<<<80, 256, 0, stream>>>(Wt, Wp, Wg, Wo, Wqkf, Wgf, Wof);
  proj_qkv<<<1024, 256, 0, stream>>>(x, Wqkf, Wgf, QbH, QbL, Kf, Vf);
  flash_attn<<<256, 512, 0, stream>>>(QbH, QbL, Kf, Vf, Wof, x, gm, out);
}